// Round 6
// baseline (170.820 us; speedup 1.0000x reference)
//
#include <hip/hip_runtime.h>
#include <stdint.h>

#define B_  4
#define T_  4096
#define D_  1024
#define HD_ 64
#define BT_ 16384   // B_*T_

typedef short bf16x8 __attribute__((ext_vector_type(8)));
typedef float f32x4  __attribute__((ext_vector_type(4)));
typedef float f32x16 __attribute__((ext_vector_type(16)));
typedef unsigned short u16;
typedef u16 u16x4 __attribute__((ext_vector_type(4)));
typedef unsigned int u32;
typedef u32 u32x4 __attribute__((ext_vector_type(4)));

#define M0L2_  11.54156032f  // M0(=8) * log2(e)
#define QSCALE_ 0.18033688f  // 0.125 * log2(e): folds softmax scale AND exp2 base

#define CPB_   264           // chunks (=attn blocks) per batch, 4 tile-tasks each
#define NSLOT_ (4 * CPB_ * 2)

__device__ __forceinline__ u16 f2bf(float f) {
    union { float f; unsigned u; } v; v.f = f;
    unsigned r = (v.u + 0x7FFF + ((v.u >> 16) & 1)) >> 16;
    return (u16)r;
}
__device__ __forceinline__ float bf2f(u16 u) {
    union { unsigned u; float f; } v; v.u = ((unsigned)u) << 16;
    return v.f;
}
// packed f32x2 -> bf16x2 (lo = first operand)
__device__ __forceinline__ u32 cvt_pk_bf16(float lo, float hi) {
    u32 r;
    asm("v_cvt_pk_bf16_f32 %0, %1, %2" : "=v"(r) : "v"(lo), "v"(hi));
    return r;
}

// ---------------------------------------------------------------------------
// Kernel 0: W fp32 -> bf16 in MFMA-FRAGMENT order.
// Fragment f = (kc*12 + colg)*2 + ks. Within a frag: lane = quad*16 + l16,
// 8 bf16/lane: element (lane,j) = W[colg*16+l16][kc*64 + ks*32 + quad*8 + j].
// ---------------------------------------------------------------------------
__global__ __launch_bounds__(256) void wconv_kernel(
    const float* __restrict__ wq, const float* __restrict__ wk,
    const float* __restrict__ wv, u16* __restrict__ wb)
{
    const int cid  = blockIdx.x * 256 + threadIdx.x;   // 96 blocks -> 24576 chunks
    const int n    = cid >> 7;          // 0..191 output col (W row)
    const int koct = cid & 127;         // k-octet 0..127
    const int mat  = n >> 6;
    const int row  = n & 63;
    const float* src = (mat == 0) ? wq : ((mat == 1) ? wk : wv);
    const float* p = src + row * 1024 + koct * 8;
    f32x4 a0 = *(const f32x4*)p;
    f32x4 a1 = *(const f32x4*)(p + 4);
    u32x4 b;
    b[0] = cvt_pk_bf16(a0[0], a0[1]);
    b[1] = cvt_pk_bf16(a0[2], a0[3]);
    b[2] = cvt_pk_bf16(a1[0], a1[1]);
    b[3] = cvt_pk_bf16(a1[2], a1[3]);
    const int kc  = koct >> 3, ksl = (koct >> 2) & 1, qd = koct & 3;
    const int f   = (kc * 12 + (n >> 4)) * 2 + ksl;
    *(u32x4*)(wb + (size_t)(f * 64 + qd * 16 + (n & 15)) * 8) = b;
}

// ---------------------------------------------------------------------------
// Kernel 1: QKV projection — zero LDS, zero barriers, NEW GEOMETRY.
// Block = 16 rows (one MFMA stripe), 4 waves = 4 col-triples (12 groups / 4).
// Grid 1024 -> 4 blocks/CU x 4 waves = 4 waves/SIMD (round-5 was grid-capped
// at 2/SIMD => latency-bound at 41 us). All waves share the block's 16 x-rows
// (L1/MSHR-coalesced); W frags stream from L1/L2 in fragment order.
// ---------------------------------------------------------------------------
__global__ __launch_bounds__(256, 4) void qkv_kernel(
    const float* __restrict__ x, const u16* __restrict__ wb,
    u16* __restrict__ qs, u16* __restrict__ kss, u16* __restrict__ vssT)
{
    const int tid  = threadIdx.x;
    const int lane = tid & 63;
    const int w    = tid >> 6;          // 0..3 -> col-triple
    const int quad = lane >> 4;
    const int l16  = lane & 15;
    const int row0 = blockIdx.x * 16;
    const int cg0  = w * 3;             // first col-group of this wave

    f32x4 acc[3];
    #pragma unroll
    for (int g = 0; g < 3; ++g) acc[g] = (f32x4)0.0f;

    const float* xq = x + (size_t)(row0 + l16) * D_ + quad * 8;
    const u16*   wp = wb + (size_t)lane * 8;

    f32x4 xr[4]; bf16x8 wc[6];
    #pragma unroll
    for (int ks = 0; ks < 2; ++ks) {
        xr[ks * 2]     = *(const f32x4*)(xq + ks * 32);
        xr[ks * 2 + 1] = *(const f32x4*)(xq + ks * 32 + 4);
    }
    #pragma unroll
    for (int g = 0; g < 3; ++g)
        #pragma unroll
        for (int ks = 0; ks < 2; ++ks)
            wc[g * 2 + ks] = *(const bf16x8*)(wp + (size_t)((cg0 + g) * 2 + ks) * 512);

    for (int kc = 0; kc < 16; ++kc) {
        f32x4 xn[4]; bf16x8 wn[6];
        if (kc < 15) {
            const float* xq1 = xq + (kc + 1) * 64;
            #pragma unroll
            for (int ks = 0; ks < 2; ++ks) {
                xn[ks * 2]     = *(const f32x4*)(xq1 + ks * 32);
                xn[ks * 2 + 1] = *(const f32x4*)(xq1 + ks * 32 + 4);
            }
            #pragma unroll
            for (int g = 0; g < 3; ++g)
                #pragma unroll
                for (int ks = 0; ks < 2; ++ks)
                    wn[g * 2 + ks] = *(const bf16x8*)(wp + (size_t)((kc + 1) * 24 + (cg0 + g) * 2 + ks) * 512);
        }
        bf16x8 a[2];
        #pragma unroll
        for (int ks = 0; ks < 2; ++ks) {
            u32x4 px;
            px[0] = cvt_pk_bf16(xr[ks * 2][0], xr[ks * 2][1]);
            px[1] = cvt_pk_bf16(xr[ks * 2][2], xr[ks * 2][3]);
            px[2] = cvt_pk_bf16(xr[ks * 2 + 1][0], xr[ks * 2 + 1][1]);
            px[3] = cvt_pk_bf16(xr[ks * 2 + 1][2], xr[ks * 2 + 1][3]);
            a[ks] = __builtin_bit_cast(bf16x8, px);
        }
        #pragma unroll
        for (int ks = 0; ks < 2; ++ks)
            #pragma unroll
            for (int g = 0; g < 3; ++g)
                acc[g] = __builtin_amdgcn_mfma_f32_16x16x32_bf16(a[ks], wc[g * 2 + ks], acc[g], 0, 0, 0);
        if (kc < 15) {
            #pragma unroll
            for (int i = 0; i < 4; ++i) xr[i] = xn[i];
            #pragma unroll
            for (int i = 0; i < 6; ++i) wc[i] = wn[i];
        }
    }
    // epilogue: C/D layout row=quad*4+r, col=l16
    #pragma unroll
    for (int g = 0; g < 3; ++g) {
        const int n = (cg0 + g) * 16 + l16;
        const int j = n >> 6, h = n & 63;
        const int rbase = row0 + quad * 4;
        if (j == 0) {
            #pragma unroll
            for (int r = 0; r < 4; ++r) qs[(size_t)(rbase + r) * HD_ + h] = f2bf(acc[g][r] * QSCALE_);
        } else if (j == 1) {
            #pragma unroll
            for (int r = 0; r < 4; ++r) kss[(size_t)(rbase + r) * HD_ + h] = f2bf(acc[g][r]);
        } else {
            u16x4 v;
            #pragma unroll
            for (int r = 0; r < 4; ++r) v[r] = f2bf(acc[g][r]);
            *(u16x4*)(vssT + (size_t)h * BT_ + rbase) = v;
        }
    }
}

// ---------------------------------------------------------------------------
// Kernel 2: flash attention, 32x32 swapped-QK, P fully in registers.
// (unchanged from round 4 — verified)
// ---------------------------------------------------------------------------
__global__ __launch_bounds__(256, 4) void attn_kernel(
    const u16* __restrict__ qs, const u16* __restrict__ kss,
    const u16* __restrict__ vssT,
    float* __restrict__ pl, u16* __restrict__ pO)
{
    __shared__ __align__(16) u16 kt2[8 * 65 * 8];
    __shared__ __align__(16) u16 vt2[8 * 65 * 8];

    const int m = blockIdx.x % CPB_;
    const int b = blockIdx.x / CPB_;

    int t0, bound, qtA, qtB;
    if (m < 240)      { int u = m >> 4; t0 = (m & 15) * 4; bound = 2 * u + 2; qtA = u;  qtB = 30 - u; }
    else if (m < 248) { t0 = (m - 240) * 4; bound = 1 << 30; qtA = 15; qtB = 15; }
    else              { t0 = (m - 248) * 4; bound = 1 << 30; qtA = 31; qtB = 31; }

    const int tid  = threadIdx.x;
    const int lane = tid & 63;
    const int w    = tid >> 6;
    const int l31  = lane & 31;
    const int hi   = lane >> 5;
    const size_t base = (size_t)b * T_;

    int qt    = (t0 < bound) ? qtA : qtB;
    int kti   = (t0 < bound) ? t0 : (t0 - bound);
    int qrow0 = qt * 128 + w * 32;

    // Q B-frags: lane holds Q[q=l31][ds*16 + hi*8 + 0..7]
    bf16x8 qf[4];
    #pragma unroll
    for (int ds = 0; ds < 4; ++ds)
        qf[ds] = *(const bf16x8*)(qs + (base + qrow0 + l31) * HD_ + ds * 16 + hi * 8);

    f32x16 o0 = (f32x16)0.0f, o1 = (f32x16)0.0f;
    float l_acc = 0.0f;

    // staging: thread t -> row t>>2 (key for K / d for V), 32B at col (t&3)*16
    const int srow = tid >> 2, q4 = tid & 3;
    const u16* kp = kss  + (base + srow) * HD_ + q4 * 16;
    const u16* vp = vssT + (size_t)srow * BT_ + base + q4 * 16;
    u16* kdst = kt2 + ((((srow >> 5) * 4 + q4) * 65 + (srow & 31)) * 8);
    u16* vdst = vt2 + ((((srow >> 5) * 4 + q4) * 65 + (srow & 31)) * 8);

    bf16x8 kr0, kr1, vr0, vr1;
    {
        const u16* k0 = kp + (size_t)kti * 64 * HD_;
        kr0 = *(const bf16x8*)k0; kr1 = *(const bf16x8*)(k0 + 8);
        const u16* v0 = vp + kti * 64;
        vr0 = *(const bf16x8*)v0; vr1 = *(const bf16x8*)(v0 + 8);
    }

    auto FLUSH = [&](int role) {
        const int slot = (b * CPB_ + m) * 2 + role;
        u32 la = __builtin_bit_cast(u32, l_acc), lb = la;
        asm("v_permlane32_swap_b32 %0, %1" : "+v"(la), "+v"(lb));
        float lfull = __builtin_bit_cast(float, la) + __builtin_bit_cast(float, lb);
        if (hi == 0) pl[slot * 128 + w * 32 + l31] = lfull;
        #pragma unroll
        for (int reg = 0; reg < 16; ++reg) {
            int row = w * 32 + (reg & 3) + 8 * (reg >> 2) + 4 * hi;
            pO[(size_t)slot * 8192 + row * 64 + l31]      = f2bf(o0[reg]);
            pO[(size_t)slot * 8192 + row * 64 + 32 + l31] = f2bf(o1[reg]);
        }
    };

    for (int step = 0; step < 4; ++step) {
        const int i = t0 + step;
        __syncthreads();
        *(bf16x8*)(kdst)       = kr0;
        *(bf16x8*)(kdst + 256) = kr1;
        *(bf16x8*)(vdst)       = vr0;
        *(bf16x8*)(vdst + 256) = vr1;
        __syncthreads();

        int kti_next = 0;
        if (step < 3) {
            kti_next = (i + 1 < bound) ? (i + 1) : (i + 1 - bound);
            const u16* k0 = kp + (size_t)kti_next * 64 * HD_;
            kr0 = *(const bf16x8*)k0; kr1 = *(const bf16x8*)(k0 + 8);
            const u16* v0 = vp + kti_next * 64;
            vr0 = *(const bf16x8*)v0; vr1 = *(const bf16x8*)(v0 + 8);
        }

        if (kti * 64 <= qrow0 + 31) {      // warp-uniform skip of fully-masked tiles
            const bool diag = (kti * 64 + 63 > qrow0);
            const int  qa   = qrow0 + l31;
            u32 wv[16];
            #pragma unroll
            for (int kg = 0; kg < 2; ++kg) {
                f32x16 s = (f32x16)0.0f;
                __builtin_amdgcn_s_setprio(1);
                #pragma unroll
                for (int ds = 0; ds < 4; ++ds) {
                    bf16x8 af = *(const bf16x8*)(kt2 + ((kg * 4 + ds) * 65 + lane) * 8);
                    s = __builtin_amdgcn_mfma_f32_32x32x16_bf16(af, qf[ds], s, 0, 0, 0);
                }
                __builtin_amdgcn_s_setprio(0);
                float lp = 0.0f;
                #pragma unroll
                for (int rp = 0; rp < 8; ++rp) {
                    float e0 = __builtin_amdgcn_exp2f(s[2 * rp]     - M0L2_);
                    float e1 = __builtin_amdgcn_exp2f(s[2 * rp + 1] - M0L2_);
                    if (diag) {
                        const int k0e = kti * 64 + kg * 32 + ((2 * rp) & 3) + 8 * ((2 * rp) >> 2) + 4 * hi;
                        if (k0e > qa)     e0 = 0.0f;
                        if (k0e + 1 > qa) e1 = 0.0f;   // reg 2rp+1 = key k0e+1
                    }
                    lp += e0 + e1;
                    wv[kg * 8 + rp] = cvt_pk_bf16(e0, e1);
                }
                l_acc += lp;
            }
            // PA frags: one swap fills two output words (guide §B recipe)
            bf16x8 pa[4];
            #pragma unroll
            for (int ks = 0; ks < 4; ++ks) {
                const int kg2 = ks >> 1, k1 = ks & 1;
                u32 x0 = wv[kg2 * 8 + k1 * 4 + 0], y0 = wv[kg2 * 8 + k1 * 4 + 2];
                u32 x1 = wv[kg2 * 8 + k1 * 4 + 1], y1 = wv[kg2 * 8 + k1 * 4 + 3];
                asm("v_permlane32_swap_b32 %0, %1" : "+v"(x0), "+v"(y0));
                asm("v_permlane32_swap_b32 %0, %1" : "+v"(x1), "+v"(y1));
                u32x4 t; t[0] = x0; t[1] = x1; t[2] = y0; t[3] = y1;
                pa[ks] = __builtin_bit_cast(bf16x8, t);
            }
            __builtin_amdgcn_s_setprio(1);
            #pragma unroll
            for (int ks = 0; ks < 4; ++ks) {
                bf16x8 vf0 = *(const bf16x8*)(vt2 + ((0 * 4 + ks) * 65 + lane) * 8);
                o0 = __builtin_amdgcn_mfma_f32_32x32x16_bf16(pa[ks], vf0, o0, 0, 0, 0);
                bf16x8 vf1 = *(const bf16x8*)(vt2 + ((1 * 4 + ks) * 65 + lane) * 8);
                o1 = __builtin_amdgcn_mfma_f32_32x32x16_bf16(pa[ks], vf1, o1, 0, 0, 0);
            }
            __builtin_amdgcn_s_setprio(0);
        }

        kti = kti_next;
        if (step < 3 && (i + 1) == bound) {   // q-tile crossing: flush + reset
            FLUSH(0);
            o0 = (f32x16)0.0f; o1 = (f32x16)0.0f; l_acc = 0.0f;
            qt = qtB; qrow0 = qt * 128 + w * 32;
            #pragma unroll
            for (int ds = 0; ds < 4; ++ds)
                qf[ds] = *(const bf16x8*)(qs + (base + qrow0 + l31) * HD_ + ds * 16 + hi * 8);
        }
    }
    FLUSH((t0 + 3 >= bound) ? 1 : 0);
}

// ---------------------------------------------------------------------------
// Kernel 3: merge partials. grid = (b, qt2, row-half) = 256 blocks.
// (unchanged from round 4 — verified)
// ---------------------------------------------------------------------------
__global__ __launch_bounds__(256) void merge_kernel(
    const float* __restrict__ pl, const u16* __restrict__ pO,
    float* __restrict__ out)
{
    const int bi  = blockIdx.x;            // b*64 + qt2*2 + rh
    const int rh  = bi & 1;
    const int qt2 = (bi >> 1) & 31;
    const int b   = bi >> 6;

    int c0, c1, role, mbase;
    if (qt2 <= 14)      { int u = qt2;      c0 = 0;                 c1 = (2 * u + 1) >> 2; role = 0; mbase = u * 16; }
    else if (qt2 == 15) { c0 = 0;           c1 = 7;                 role = 0; mbase = 240; }
    else if (qt2 <= 30) { int u = 30 - qt2; c0 = (2 * u + 2) >> 2;  c1 = 15; role = 1; mbase = u * 16; }
    else                { c0 = 0;           c1 = 15;                role = 0; mbase = 248; }

    const int row = rh * 64 + (threadIdx.x >> 2);
    const int hg  = (threadIdx.x & 3) * 16;

    float L = 0.0f;
    float o[16];
    #pragma unroll
    for (int i = 0; i < 16; ++i) o[i] = 0.0f;
    for (int c = c0; c <= c1; ++c) {
        const int slot = (b * CPB_ + mbase + c) * 2 + role;
        L += pl[slot * 128 + row];
        const u16* p = pO + (size_t)slot * 8192 + row * 64 + hg;
        bf16x8 v0 = *(const bf16x8*)p;
        bf16x8 v1 = *(const bf16x8*)(p + 8);
        #pragma unroll
        for (int i = 0; i < 8; ++i) { o[i] += bf2f((u16)v0[i]); o[8 + i] += bf2f((u16)v1[i]); }
    }
    const float inv = 1.0f / L;
    float* op = out + ((size_t)b * T_ + qt2 * 128 + row) * HD_ + hg;
    #pragma unroll
    for (int j = 0; j < 4; ++j) {
        f32x4 v;
        #pragma unroll
        for (int i = 0; i < 4; ++i) v[i] = o[j * 4 + i] * inv;
        *(f32x4*)(op + j * 4) = v;
    }
}

extern "C" void kernel_launch(void* const* d_in, const int* in_sizes, int n_in,
                              void* d_out, int out_size, void* d_ws, size_t ws_size,
                              hipStream_t stream) {
    const float* x  = (const float*)d_in[0];
    const float* wq = (const float*)d_in[1];
    const float* wk = (const float*)d_in[2];
    const float* wv = (const float*)d_in[3];

    const size_t NE = (size_t)BT_ * HD_;           // 1,048,576
    char* ws = (char*)d_ws;
    u16* qs   = (u16*)ws;                          // 2 MB (Q pre-scaled)
    u16* kss  = qs  + NE;                          // 2 MB
    u16* vssT = kss + NE;                          // 2 MB, [h][B*T]
    u16* wb   = vssT + NE;                         // 384 KB bf16 W (fragment order)
    float* pl = (float*)(wb + 192 * 1024);         // NSLOT_*128 f32 = 1.08 MB
    u16* pO   = (u16*)(pl + (size_t)NSLOT_ * 128); // NSLOT_*8192 bf16 = 34.6 MB
    float* out = (float*)d_out;

    wconv_kernel<<<dim3(96),        dim3(256), 0, stream>>>(wq, wk, wv, wb);
    qkv_kernel  <<<dim3(1024),      dim3(256), 0, stream>>>(x, wb, qs, kss, vssT);
    attn_kernel <<<dim3(4 * CPB_),  dim3(256), 0, stream>>>(qs, kss, vssT, pl, pO);
    merge_kernel<<<dim3(256),       dim3(256), 0, stream>>>(pl, pO, out);
}

// Round 7
// 150.933 us; speedup vs baseline: 1.1318x; 1.1318x over previous
//
#include <hip/hip_runtime.h>
#include <stdint.h>

#define B_  4
#define T_  4096
#define D_  1024
#define HD_ 64
#define BT_ 16384   // B_*T_

typedef short bf16x8 __attribute__((ext_vector_type(8)));
typedef float f32x4  __attribute__((ext_vector_type(4)));
typedef float f32x16 __attribute__((ext_vector_type(16)));
typedef unsigned short u16;
typedef u16 u16x4 __attribute__((ext_vector_type(4)));
typedef unsigned int u32;
typedef u32 u32x4 __attribute__((ext_vector_type(4)));

#define M0L2_  11.54156032f  // M0(=8) * log2(e)
#define QSCALE_ 0.18033688f  // 0.125 * log2(e): folds softmax scale AND exp2 base

#define CPB_   264           // chunks (=attn blocks) per batch, 4 tile-tasks each
#define NSLOT_ (4 * CPB_ * 2)

__device__ __forceinline__ u16 f2bf(float f) {
    union { float f; unsigned u; } v; v.f = f;
    unsigned r = (v.u + 0x7FFF + ((v.u >> 16) & 1)) >> 16;
    return (u16)r;
}
__device__ __forceinline__ float bf2f(u16 u) {
    union { unsigned u; float f; } v; v.u = ((unsigned)u) << 16;
    return v.f;
}
// packed f32x2 -> bf16x2 (lo = first operand)
__device__ __forceinline__ u32 cvt_pk_bf16(float lo, float hi) {
    u32 r;
    asm("v_cvt_pk_bf16_f32 %0, %1, %2" : "=v"(r) : "v"(lo), "v"(hi));
    return r;
}

// ---------------------------------------------------------------------------
// Kernel 0: W fp32 -> packed bf16 [192][1024] row-major (rows 0-63 Wq,
// 64-127 Wk, 128-191 Wv). (Reverted to round-1 layout for LDS-staged qkv.)
// ---------------------------------------------------------------------------
__global__ __launch_bounds__(256) void wconv_kernel(
    const float* __restrict__ wq, const float* __restrict__ wk,
    const float* __restrict__ wv, u16* __restrict__ wb)
{
    const int j   = blockIdx.x >> 5;
    const int off = (blockIdx.x & 31) * 2048 + threadIdx.x * 8;
    const float* src = (j == 0) ? wq : ((j == 1) ? wk : wv);
    f32x4 a0 = *(const f32x4*)(src + off);
    f32x4 a1 = *(const f32x4*)(src + off + 4);
    u32x4 b;
    b[0] = cvt_pk_bf16(a0[0], a0[1]);
    b[1] = cvt_pk_bf16(a0[2], a0[3]);
    b[2] = cvt_pk_bf16(a1[0], a1[1]);
    b[3] = cvt_pk_bf16(a1[2], a1[3]);
    *(u32x4*)(wb + j * 65536 + off) = b;
}

// ---------------------------------------------------------------------------
// Kernel 1: QKV projection — round-1 LDS-staged skeleton (cooperative
// coalesced global->reg prefetch one kc ahead, staged to LDS; THIS is what
// hides latency — rounds 5/6 proved direct-from-L2 register pipelining
// collapses in the compiler).
// NEW GEOMETRY ONLY: 64-row tiles, 512 threads (8 waves = 2 row-halves x
// 4 col-triples), grid 256 = 1 block/CU exactly.
// LDS ledger/wave/kc: 4 writes + 10 reads b128 (was 7+14) and each kc-window
// covers 64 rows (was 32) -> per-CU LDS cycles ~3x lower => ~13-16 us.
// Emits: qs[row][h] (x 0.125*log2e), kss[row][h], vssT[h][row] (transposed).
// ---------------------------------------------------------------------------
__global__ __launch_bounds__(512) void qkv_kernel(
    const float* __restrict__ x, const u16* __restrict__ wb,
    u16* __restrict__ qs, u16* __restrict__ kss, u16* __restrict__ vssT)
{
    __shared__ __align__(16) u16 xt[64][72];
    __shared__ __align__(16) u16 wt[192][72];

    const int tid  = threadIdx.x;
    const int lane = tid & 63;
    const int w    = tid >> 6;          // 0..7
    const int quad = lane >> 4;
    const int l16  = lane & 15;
    const int row0 = blockIdx.x * 64;
    const int rh   = w >> 2;            // row-half (32 rows)
    const int ct   = w & 3;             // col-triple (3 col-groups of 16)

    const int xrow = tid >> 3;          // 0..63  (x staging row)
    const int xcg  = tid & 7;           // col-group *8

    f32x4 acc[2][3];
    #pragma unroll
    for (int s = 0; s < 2; ++s)
        #pragma unroll
        for (int g = 0; g < 3; ++g) acc[s][g] = (f32x4)0.0f;

    // prefetch registers (kc = 0)
    f32x4 xa, xb;
    bf16x8 wr[3];
    {
        const float* xp = x + (size_t)(row0 + xrow) * D_ + xcg * 8;
        xa = *(const f32x4*)xp; xb = *(const f32x4*)(xp + 4);
        #pragma unroll
        for (int i = 0; i < 3; ++i) {
            int chunk = tid + 512 * i;          // 1536 chunks = 192 rows x 8 cg
            wr[i] = *(const bf16x8*)(wb + (size_t)(chunk >> 3) * D_ + (chunk & 7) * 8);
        }
    }

    for (int kc = 0; kc < 16; ++kc) {
        __syncthreads();
        {
            u32x4 px;
            px[0] = cvt_pk_bf16(xa[0], xa[1]);
            px[1] = cvt_pk_bf16(xa[2], xa[3]);
            px[2] = cvt_pk_bf16(xb[0], xb[1]);
            px[3] = cvt_pk_bf16(xb[2], xb[3]);
            *(u32x4*)&xt[xrow][xcg * 8] = px;
            #pragma unroll
            for (int i = 0; i < 3; ++i) {
                int chunk = tid + 512 * i;
                *(bf16x8*)&wt[chunk >> 3][(chunk & 7) * 8] = wr[i];
            }
        }
        __syncthreads();
        if (kc < 15) {
            const float* xp = x + (size_t)(row0 + xrow) * D_ + (kc + 1) * 64 + xcg * 8;
            xa = *(const f32x4*)xp; xb = *(const f32x4*)(xp + 4);
            #pragma unroll
            for (int i = 0; i < 3; ++i) {
                int chunk = tid + 512 * i;
                wr[i] = *(const bf16x8*)(wb + (size_t)(chunk >> 3) * D_ + (kc + 1) * 64 + (chunk & 7) * 8);
            }
        }
        #pragma unroll
        for (int ks = 0; ks < 2; ++ks) {
            bf16x8 a[2];
            #pragma unroll
            for (int s = 0; s < 2; ++s)
                a[s] = *(const bf16x8*)&xt[rh * 32 + s * 16 + l16][ks * 32 + quad * 8];
            #pragma unroll
            for (int g = 0; g < 3; ++g) {
                bf16x8 bfr = *(const bf16x8*)&wt[(ct * 3 + g) * 16 + l16][ks * 32 + quad * 8];
                #pragma unroll
                for (int s = 0; s < 2; ++s)
                    acc[s][g] = __builtin_amdgcn_mfma_f32_16x16x32_bf16(a[s], bfr, acc[s][g], 0, 0, 0);
            }
        }
    }
    // epilogue: C/D layout row=quad*4+r, col=l16
    #pragma unroll
    for (int s = 0; s < 2; ++s) {
        #pragma unroll
        for (int g = 0; g < 3; ++g) {
            const int n = (ct * 3 + g) * 16 + l16;
            const int j = n >> 6, h = n & 63;
            const int rbase = row0 + rh * 32 + s * 16 + quad * 4;
            if (j == 0) {
                #pragma unroll
                for (int r = 0; r < 4; ++r) qs[(size_t)(rbase + r) * HD_ + h] = f2bf(acc[s][g][r] * QSCALE_);
            } else if (j == 1) {
                #pragma unroll
                for (int r = 0; r < 4; ++r) kss[(size_t)(rbase + r) * HD_ + h] = f2bf(acc[s][g][r]);
            } else {
                u16x4 v;
                #pragma unroll
                for (int r = 0; r < 4; ++r) v[r] = f2bf(acc[s][g][r]);
                *(u16x4*)(vssT + (size_t)h * BT_ + rbase) = v;   // transposed store
            }
        }
    }
}

// ---------------------------------------------------------------------------
// Kernel 2: flash attention, 32x32 swapped-QK, P fully in registers.
// (unchanged from round 4 — verified)
// ---------------------------------------------------------------------------
__global__ __launch_bounds__(256, 4) void attn_kernel(
    const u16* __restrict__ qs, const u16* __restrict__ kss,
    const u16* __restrict__ vssT,
    float* __restrict__ pl, u16* __restrict__ pO)
{
    __shared__ __align__(16) u16 kt2[8 * 65 * 8];
    __shared__ __align__(16) u16 vt2[8 * 65 * 8];

    const int m = blockIdx.x % CPB_;
    const int b = blockIdx.x / CPB_;

    int t0, bound, qtA, qtB;
    if (m < 240)      { int u = m >> 4; t0 = (m & 15) * 4; bound = 2 * u + 2; qtA = u;  qtB = 30 - u; }
    else if (m < 248) { t0 = (m - 240) * 4; bound = 1 << 30; qtA = 15; qtB = 15; }
    else              { t0 = (m - 248) * 4; bound = 1 << 30; qtA = 31; qtB = 31; }

    const int tid  = threadIdx.x;
    const int lane = tid & 63;
    const int w    = tid >> 6;
    const int l31  = lane & 31;
    const int hi   = lane >> 5;
    const size_t base = (size_t)b * T_;

    int qt    = (t0 < bound) ? qtA : qtB;
    int kti   = (t0 < bound) ? t0 : (t0 - bound);
    int qrow0 = qt * 128 + w * 32;

    // Q B-frags: lane holds Q[q=l31][ds*16 + hi*8 + 0..7]
    bf16x8 qf[4];
    #pragma unroll
    for (int ds = 0; ds < 4; ++ds)
        qf[ds] = *(const bf16x8*)(qs + (base + qrow0 + l31) * HD_ + ds * 16 + hi * 8);

    f32x16 o0 = (f32x16)0.0f, o1 = (f32x16)0.0f;
    float l_acc = 0.0f;

    // staging: thread t -> row t>>2 (key for K / d for V), 32B at col (t&3)*16
    const int srow = tid >> 2, q4 = tid & 3;
    const u16* kp = kss  + (base + srow) * HD_ + q4 * 16;
    const u16* vp = vssT + (size_t)srow * BT_ + base + q4 * 16;
    u16* kdst = kt2 + ((((srow >> 5) * 4 + q4) * 65 + (srow & 31)) * 8);
    u16* vdst = vt2 + ((((srow >> 5) * 4 + q4) * 65 + (srow & 31)) * 8);

    bf16x8 kr0, kr1, vr0, vr1;
    {
        const u16* k0 = kp + (size_t)kti * 64 * HD_;
        kr0 = *(const bf16x8*)k0; kr1 = *(const bf16x8*)(k0 + 8);
        const u16* v0 = vp + kti * 64;
        vr0 = *(const bf16x8*)v0; vr1 = *(const bf16x8*)(v0 + 8);
    }

    auto FLUSH = [&](int role) {
        const int slot = (b * CPB_ + m) * 2 + role;
        u32 la = __builtin_bit_cast(u32, l_acc), lb = la;
        asm("v_permlane32_swap_b32 %0, %1" : "+v"(la), "+v"(lb));
        float lfull = __builtin_bit_cast(float, la) + __builtin_bit_cast(float, lb);
        if (hi == 0) pl[slot * 128 + w * 32 + l31] = lfull;
        #pragma unroll
        for (int reg = 0; reg < 16; ++reg) {
            int row = w * 32 + (reg & 3) + 8 * (reg >> 2) + 4 * hi;
            pO[(size_t)slot * 8192 + row * 64 + l31]      = f2bf(o0[reg]);
            pO[(size_t)slot * 8192 + row * 64 + 32 + l31] = f2bf(o1[reg]);
        }
    };

    for (int step = 0; step < 4; ++step) {
        const int i = t0 + step;
        __syncthreads();
        *(bf16x8*)(kdst)       = kr0;
        *(bf16x8*)(kdst + 256) = kr1;
        *(bf16x8*)(vdst)       = vr0;
        *(bf16x8*)(vdst + 256) = vr1;
        __syncthreads();

        int kti_next = 0;
        if (step < 3) {
            kti_next = (i + 1 < bound) ? (i + 1) : (i + 1 - bound);
            const u16* k0 = kp + (size_t)kti_next * 64 * HD_;
            kr0 = *(const bf16x8*)k0; kr1 = *(const bf16x8*)(k0 + 8);
            const u16* v0 = vp + kti_next * 64;
            vr0 = *(const bf16x8*)v0; vr1 = *(const bf16x8*)(v0 + 8);
        }

        if (kti * 64 <= qrow0 + 31) {      // warp-uniform skip of fully-masked tiles
            const bool diag = (kti * 64 + 63 > qrow0);
            const int  qa   = qrow0 + l31;
            u32 wv[16];
            #pragma unroll
            for (int kg = 0; kg < 2; ++kg) {
                f32x16 s = (f32x16)0.0f;
                __builtin_amdgcn_s_setprio(1);
                #pragma unroll
                for (int ds = 0; ds < 4; ++ds) {
                    bf16x8 af = *(const bf16x8*)(kt2 + ((kg * 4 + ds) * 65 + lane) * 8);
                    s = __builtin_amdgcn_mfma_f32_32x32x16_bf16(af, qf[ds], s, 0, 0, 0);
                }
                __builtin_amdgcn_s_setprio(0);
                float lp = 0.0f;
                #pragma unroll
                for (int rp = 0; rp < 8; ++rp) {
                    float e0 = __builtin_amdgcn_exp2f(s[2 * rp]     - M0L2_);
                    float e1 = __builtin_amdgcn_exp2f(s[2 * rp + 1] - M0L2_);
                    if (diag) {
                        const int k0e = kti * 64 + kg * 32 + ((2 * rp) & 3) + 8 * ((2 * rp) >> 2) + 4 * hi;
                        if (k0e > qa)     e0 = 0.0f;
                        if (k0e + 1 > qa) e1 = 0.0f;   // reg 2rp+1 = key k0e+1
                    }
                    lp += e0 + e1;
                    wv[kg * 8 + rp] = cvt_pk_bf16(e0, e1);
                }
                l_acc += lp;
            }
            // PA frags: one swap fills two output words (guide §B recipe)
            bf16x8 pa[4];
            #pragma unroll
            for (int ks = 0; ks < 4; ++ks) {
                const int kg2 = ks >> 1, k1 = ks & 1;
                u32 x0 = wv[kg2 * 8 + k1 * 4 + 0], y0 = wv[kg2 * 8 + k1 * 4 + 2];
                u32 x1 = wv[kg2 * 8 + k1 * 4 + 1], y1 = wv[kg2 * 8 + k1 * 4 + 3];
                asm("v_permlane32_swap_b32 %0, %1" : "+v"(x0), "+v"(y0));
                asm("v_permlane32_swap_b32 %0, %1" : "+v"(x1), "+v"(y1));
                u32x4 t; t[0] = x0; t[1] = x1; t[2] = y0; t[3] = y1;
                pa[ks] = __builtin_bit_cast(bf16x8, t);
            }
            __builtin_amdgcn_s_setprio(1);
            #pragma unroll
            for (int ks = 0; ks < 4; ++ks) {
                bf16x8 vf0 = *(const bf16x8*)(vt2 + ((0 * 4 + ks) * 65 + lane) * 8);
                o0 = __builtin_amdgcn_mfma_f32_32x32x16_bf16(pa[ks], vf0, o0, 0, 0, 0);
                bf16x8 vf1 = *(const bf16x8*)(vt2 + ((1 * 4 + ks) * 65 + lane) * 8);
                o1 = __builtin_amdgcn_mfma_f32_32x32x16_bf16(pa[ks], vf1, o1, 0, 0, 0);
            }
            __builtin_amdgcn_s_setprio(0);
        }

        kti = kti_next;
        if (step < 3 && (i + 1) == bound) {   // q-tile crossing: flush + reset
            FLUSH(0);
            o0 = (f32x16)0.0f; o1 = (f32x16)0.0f; l_acc = 0.0f;
            qt = qtB; qrow0 = qt * 128 + w * 32;
            #pragma unroll
            for (int ds = 0; ds < 4; ++ds)
                qf[ds] = *(const bf16x8*)(qs + (base + qrow0 + l31) * HD_ + ds * 16 + hi * 8);
        }
    }
    FLUSH((t0 + 3 >= bound) ? 1 : 0);
}

// ---------------------------------------------------------------------------
// Kernel 3: merge partials. grid = (b, qt2, row-half) = 256 blocks.
// (unchanged from round 4 — verified)
// ---------------------------------------------------------------------------
__global__ __launch_bounds__(256) void merge_kernel(
    const float* __restrict__ pl, const u16* __restrict__ pO,
    float* __restrict__ out)
{
    const int bi  = blockIdx.x;            // b*64 + qt2*2 + rh
    const int rh  = bi & 1;
    const int qt2 = (bi >> 1) & 31;
    const int b   = bi >> 6;

    int c0, c1, role, mbase;
    if (qt2 <= 14)      { int u = qt2;      c0 = 0;                 c1 = (2 * u + 1) >> 2; role = 0; mbase = u * 16; }
    else if (qt2 == 15) { c0 = 0;           c1 = 7;                 role = 0; mbase = 240; }
    else if (qt2 <= 30) { int u = 30 - qt2; c0 = (2 * u + 2) >> 2;  c1 = 15; role = 1; mbase = u * 16; }
    else                { c0 = 0;           c1 = 15;                role = 0; mbase = 248; }

    const int row = rh * 64 + (threadIdx.x >> 2);
    const int hg  = (threadIdx.x & 3) * 16;

    float L = 0.0f;
    float o[16];
    #pragma unroll
    for (int i = 0; i < 16; ++i) o[i] = 0.0f;
    for (int c = c0; c <= c1; ++c) {
        const int slot = (b * CPB_ + mbase + c) * 2 + role;
        L += pl[slot * 128 + row];
        const u16* p = pO + (size_t)slot * 8192 + row * 64 + hg;
        bf16x8 v0 = *(const bf16x8*)p;
        bf16x8 v1 = *(const bf16x8*)(p + 8);
        #pragma unroll
        for (int i = 0; i < 8; ++i) { o[i] += bf2f((u16)v0[i]); o[8 + i] += bf2f((u16)v1[i]); }
    }
    const float inv = 1.0f / L;
    float* op = out + ((size_t)b * T_ + qt2 * 128 + row) * HD_ + hg;
    #pragma unroll
    for (int j = 0; j < 4; ++j) {
        f32x4 v;
        #pragma unroll
        for (int i = 0; i < 4; ++i) v[i] = o[j * 4 + i] * inv;
        *(f32x4*)(op + j * 4) = v;
    }
}

extern "C" void kernel_launch(void* const* d_in, const int* in_sizes, int n_in,
                              void* d_out, int out_size, void* d_ws, size_t ws_size,
                              hipStream_t stream) {
    const float* x  = (const float*)d_in[0];
    const float* wq = (const float*)d_in[1];
    const float* wk = (const float*)d_in[2];
    const float* wv = (const float*)d_in[3];

    const size_t NE = (size_t)BT_ * HD_;           // 1,048,576
    char* ws = (char*)d_ws;
    u16* qs   = (u16*)ws;                          // 2 MB (Q pre-scaled)
    u16* kss  = qs  + NE;                          // 2 MB
    u16* vssT = kss + NE;                          // 2 MB, [h][B*T]
    u16* wb   = vssT + NE;                         // 384 KB bf16 W (row-major)
    float* pl = (float*)(wb + 192 * 1024);         // NSLOT_*128 f32 = 1.08 MB
    u16* pO   = (u16*)(pl + (size_t)NSLOT_ * 128); // NSLOT_*8192 bf16 = 34.6 MB
    float* out = (float*)d_out;

    wconv_kernel<<<dim3(96),        dim3(256), 0, stream>>>(wq, wk, wv, wb);
    qkv_kernel  <<<dim3(256),       dim3(512), 0, stream>>>(x, wb, qs, kss, vssT);
    attn_kernel <<<dim3(4 * CPB_),  dim3(256), 0, stream>>>(qs, kss, vssT, pl, pO);
    merge_kernel<<<dim3(256),       dim3(256), 0, stream>>>(pl, pO, out);
}

// Round 8
// 146.437 us; speedup vs baseline: 1.1665x; 1.0307x over previous
//
#include <hip/hip_runtime.h>
#include <stdint.h>

#define B_  4
#define T_  4096
#define D_  1024
#define HD_ 64
#define BT_ 16384   // B_*T_

typedef short bf16x8 __attribute__((ext_vector_type(8)));
typedef float f32x4  __attribute__((ext_vector_type(4)));
typedef float f32x16 __attribute__((ext_vector_type(16)));
typedef unsigned short u16;
typedef u16 u16x4 __attribute__((ext_vector_type(4)));
typedef unsigned int u32;
typedef u32 u32x4 __attribute__((ext_vector_type(4)));

#define M0L2_  11.54156032f  // M0(=8) * log2(e)
#define QSCALE_ 0.18033688f  // 0.125 * log2(e): folds softmax scale AND exp2 base

#define CPB_   264           // chunks (=attn blocks) per batch, 4 tile-tasks each
#define NSLOT_ (4 * CPB_ * 2)

__device__ __forceinline__ u16 f2bf(float f) {
    union { float f; unsigned u; } v; v.f = f;
    unsigned r = (v.u + 0x7FFF + ((v.u >> 16) & 1)) >> 16;
    return (u16)r;
}
__device__ __forceinline__ float bf2f(u16 u) {
    union { unsigned u; float f; } v; v.u = ((unsigned)u) << 16;
    return v.f;
}
// packed f32x2 -> bf16x2 (lo = first operand)
__device__ __forceinline__ u32 cvt_pk_bf16(float lo, float hi) {
    u32 r;
    asm("v_cvt_pk_bf16_f32 %0, %1, %2" : "=v"(r) : "v"(lo), "v"(hi));
    return r;
}

// ---------------------------------------------------------------------------
// Kernel 0: W fp32 -> packed bf16 [192][1024] row-major (rows 0-63 Wq,
// 64-127 Wk, 128-191 Wv).
// ---------------------------------------------------------------------------
__global__ __launch_bounds__(256) void wconv_kernel(
    const float* __restrict__ wq, const float* __restrict__ wk,
    const float* __restrict__ wv, u16* __restrict__ wb)
{
    const int j   = blockIdx.x >> 5;
    const int off = (blockIdx.x & 31) * 2048 + threadIdx.x * 8;
    const float* src = (j == 0) ? wq : ((j == 1) ? wk : wv);
    f32x4 a0 = *(const f32x4*)(src + off);
    f32x4 a1 = *(const f32x4*)(src + off + 4);
    u32x4 b;
    b[0] = cvt_pk_bf16(a0[0], a0[1]);
    b[1] = cvt_pk_bf16(a0[2], a0[3]);
    b[2] = cvt_pk_bf16(a1[0], a1[1]);
    b[3] = cvt_pk_bf16(a1[2], a1[3]);
    *(u32x4*)(wb + j * 65536 + off) = b;
}

// ---------------------------------------------------------------------------
// Kernel 1: QKV projection — 64-row tiles, 512 threads, DOUBLE-BUFFERED LDS,
// ONE barrier per kc. Round 7 proved the 64-row ledger is right but 1
// block/CU exposes the full barrier drain (no cross-block overlap); the
// double buffer restores overlap WITHIN the block: compute(buf[cur]) runs
// while next-tile global loads are in flight; ds_write(buf[cur^1]) waits
// vmcnt only after ~220 cy of ds_read+MFMA.
// Emits: qs[row][h] (x 0.125*log2e), kss[row][h], vssT[h][row] (transposed).
// ---------------------------------------------------------------------------
__global__ __launch_bounds__(512) void qkv_kernel(
    const float* __restrict__ x, const u16* __restrict__ wb,
    u16* __restrict__ qs, u16* __restrict__ kss, u16* __restrict__ vssT)
{
    __shared__ __align__(16) u16 xt[2][64][72];
    __shared__ __align__(16) u16 wt[2][192][72];

    const int tid  = threadIdx.x;
    const int lane = tid & 63;
    const int w    = tid >> 6;          // 0..7
    const int quad = lane >> 4;
    const int l16  = lane & 15;
    const int row0 = blockIdx.x * 64;
    const int rh   = w >> 2;            // row-half (32 rows)
    const int ct   = w & 3;             // col-triple (3 col-groups of 16)

    const int xrow = tid >> 3;          // 0..63  (x staging row)
    const int xcg  = tid & 7;           // col-group *8

    f32x4 acc[2][3];
    #pragma unroll
    for (int s = 0; s < 2; ++s)
        #pragma unroll
        for (int g = 0; g < 3; ++g) acc[s][g] = (f32x4)0.0f;

    // staging registers
    f32x4 xa, xb;
    bf16x8 wr[3];

    // prologue: load tile 0, write buffer 0
    {
        const float* xp = x + (size_t)(row0 + xrow) * D_ + xcg * 8;
        xa = *(const f32x4*)xp; xb = *(const f32x4*)(xp + 4);
        #pragma unroll
        for (int i = 0; i < 3; ++i) {
            int chunk = tid + 512 * i;          // 1536 chunks = 192 rows x 8 cg
            wr[i] = *(const bf16x8*)(wb + (size_t)(chunk >> 3) * D_ + (chunk & 7) * 8);
        }
        u32x4 px;
        px[0] = cvt_pk_bf16(xa[0], xa[1]);
        px[1] = cvt_pk_bf16(xa[2], xa[3]);
        px[2] = cvt_pk_bf16(xb[0], xb[1]);
        px[3] = cvt_pk_bf16(xb[2], xb[3]);
        *(u32x4*)&xt[0][xrow][xcg * 8] = px;
        #pragma unroll
        for (int i = 0; i < 3; ++i) {
            int chunk = tid + 512 * i;
            *(bf16x8*)&wt[0][chunk >> 3][(chunk & 7) * 8] = wr[i];
        }
    }
    __syncthreads();

    for (int kc = 0; kc < 16; ++kc) {
        const int cur = kc & 1;
        // issue next-tile global loads FIRST (latency hides under compute)
        if (kc < 15) {
            const float* xp = x + (size_t)(row0 + xrow) * D_ + (kc + 1) * 64 + xcg * 8;
            xa = *(const f32x4*)xp; xb = *(const f32x4*)(xp + 4);
            #pragma unroll
            for (int i = 0; i < 3; ++i) {
                int chunk = tid + 512 * i;
                wr[i] = *(const bf16x8*)(wb + (size_t)(chunk >> 3) * D_ + (kc + 1) * 64 + (chunk & 7) * 8);
            }
        }
        // compute from buf[cur]
        #pragma unroll
        for (int ks = 0; ks < 2; ++ks) {
            bf16x8 a[2];
            #pragma unroll
            for (int s = 0; s < 2; ++s)
                a[s] = *(const bf16x8*)&xt[cur][rh * 32 + s * 16 + l16][ks * 32 + quad * 8];
            #pragma unroll
            for (int g = 0; g < 3; ++g) {
                bf16x8 bfr = *(const bf16x8*)&wt[cur][(ct * 3 + g) * 16 + l16][ks * 32 + quad * 8];
                #pragma unroll
                for (int s = 0; s < 2; ++s)
                    acc[s][g] = __builtin_amdgcn_mfma_f32_16x16x32_bf16(a[s], bfr, acc[s][g], 0, 0, 0);
            }
        }
        // stage next tile into buf[cur^1]
        if (kc < 15) {
            u32x4 px;
            px[0] = cvt_pk_bf16(xa[0], xa[1]);
            px[1] = cvt_pk_bf16(xa[2], xa[3]);
            px[2] = cvt_pk_bf16(xb[0], xb[1]);
            px[3] = cvt_pk_bf16(xb[2], xb[3]);
            *(u32x4*)&xt[cur ^ 1][xrow][xcg * 8] = px;
            #pragma unroll
            for (int i = 0; i < 3; ++i) {
                int chunk = tid + 512 * i;
                *(bf16x8*)&wt[cur ^ 1][chunk >> 3][(chunk & 7) * 8] = wr[i];
            }
        }
        __syncthreads();
    }
    // epilogue: C/D layout row=quad*4+r, col=l16
    #pragma unroll
    for (int s = 0; s < 2; ++s) {
        #pragma unroll
        for (int g = 0; g < 3; ++g) {
            const int n = (ct * 3 + g) * 16 + l16;
            const int j = n >> 6, h = n & 63;
            const int rbase = row0 + rh * 32 + s * 16 + quad * 4;
            if (j == 0) {
                #pragma unroll
                for (int r = 0; r < 4; ++r) qs[(size_t)(rbase + r) * HD_ + h] = f2bf(acc[s][g][r] * QSCALE_);
            } else if (j == 1) {
                #pragma unroll
                for (int r = 0; r < 4; ++r) kss[(size_t)(rbase + r) * HD_ + h] = f2bf(acc[s][g][r]);
            } else {
                u16x4 v;
                #pragma unroll
                for (int r = 0; r < 4; ++r) v[r] = f2bf(acc[s][g][r]);
                *(u16x4*)(vssT + (size_t)h * BT_ + rbase) = v;   // transposed store
            }
        }
    }
}

// ---------------------------------------------------------------------------
// Kernel 2: flash attention, 32x32 swapped-QK, P fully in registers.
// (unchanged from round 4 — verified)
// ---------------------------------------------------------------------------
__global__ __launch_bounds__(256, 4) void attn_kernel(
    const u16* __restrict__ qs, const u16* __restrict__ kss,
    const u16* __restrict__ vssT,
    float* __restrict__ pl, u16* __restrict__ pO)
{
    __shared__ __align__(16) u16 kt2[8 * 65 * 8];
    __shared__ __align__(16) u16 vt2[8 * 65 * 8];

    const int m = blockIdx.x % CPB_;
    const int b = blockIdx.x / CPB_;

    int t0, bound, qtA, qtB;
    if (m < 240)      { int u = m >> 4; t0 = (m & 15) * 4; bound = 2 * u + 2; qtA = u;  qtB = 30 - u; }
    else if (m < 248) { t0 = (m - 240) * 4; bound = 1 << 30; qtA = 15; qtB = 15; }
    else              { t0 = (m - 248) * 4; bound = 1 << 30; qtA = 31; qtB = 31; }

    const int tid  = threadIdx.x;
    const int lane = tid & 63;
    const int w    = tid >> 6;
    const int l31  = lane & 31;
    const int hi   = lane >> 5;
    const size_t base = (size_t)b * T_;

    int qt    = (t0 < bound) ? qtA : qtB;
    int kti   = (t0 < bound) ? t0 : (t0 - bound);
    int qrow0 = qt * 128 + w * 32;

    // Q B-frags: lane holds Q[q=l31][ds*16 + hi*8 + 0..7]
    bf16x8 qf[4];
    #pragma unroll
    for (int ds = 0; ds < 4; ++ds)
        qf[ds] = *(const bf16x8*)(qs + (base + qrow0 + l31) * HD_ + ds * 16 + hi * 8);

    f32x16 o0 = (f32x16)0.0f, o1 = (f32x16)0.0f;
    float l_acc = 0.0f;

    // staging: thread t -> row t>>2 (key for K / d for V), 32B at col (t&3)*16
    const int srow = tid >> 2, q4 = tid & 3;
    const u16* kp = kss  + (base + srow) * HD_ + q4 * 16;
    const u16* vp = vssT + (size_t)srow * BT_ + base + q4 * 16;
    u16* kdst = kt2 + ((((srow >> 5) * 4 + q4) * 65 + (srow & 31)) * 8);
    u16* vdst = vt2 + ((((srow >> 5) * 4 + q4) * 65 + (srow & 31)) * 8);

    bf16x8 kr0, kr1, vr0, vr1;
    {
        const u16* k0 = kp + (size_t)kti * 64 * HD_;
        kr0 = *(const bf16x8*)k0; kr1 = *(const bf16x8*)(k0 + 8);
        const u16* v0 = vp + kti * 64;
        vr0 = *(const bf16x8*)v0; vr1 = *(const bf16x8*)(v0 + 8);
    }

    auto FLUSH = [&](int role) {
        const int slot = (b * CPB_ + m) * 2 + role;
        u32 la = __builtin_bit_cast(u32, l_acc), lb = la;
        asm("v_permlane32_swap_b32 %0, %1" : "+v"(la), "+v"(lb));
        float lfull = __builtin_bit_cast(float, la) + __builtin_bit_cast(float, lb);
        if (hi == 0) pl[slot * 128 + w * 32 + l31] = lfull;
        #pragma unroll
        for (int reg = 0; reg < 16; ++reg) {
            int row = w * 32 + (reg & 3) + 8 * (reg >> 2) + 4 * hi;
            pO[(size_t)slot * 8192 + row * 64 + l31]      = f2bf(o0[reg]);
            pO[(size_t)slot * 8192 + row * 64 + 32 + l31] = f2bf(o1[reg]);
        }
    };

    for (int step = 0; step < 4; ++step) {
        const int i = t0 + step;
        __syncthreads();
        *(bf16x8*)(kdst)       = kr0;
        *(bf16x8*)(kdst + 256) = kr1;
        *(bf16x8*)(vdst)       = vr0;
        *(bf16x8*)(vdst + 256) = vr1;
        __syncthreads();

        int kti_next = 0;
        if (step < 3) {
            kti_next = (i + 1 < bound) ? (i + 1) : (i + 1 - bound);
            const u16* k0 = kp + (size_t)kti_next * 64 * HD_;
            kr0 = *(const bf16x8*)k0; kr1 = *(const bf16x8*)(k0 + 8);
            const u16* v0 = vp + kti_next * 64;
            vr0 = *(const bf16x8*)v0; vr1 = *(const bf16x8*)(v0 + 8);
        }

        if (kti * 64 <= qrow0 + 31) {      // warp-uniform skip of fully-masked tiles
            const bool diag = (kti * 64 + 63 > qrow0);
            const int  qa   = qrow0 + l31;
            u32 wv[16];
            #pragma unroll
            for (int kg = 0; kg < 2; ++kg) {
                f32x16 s = (f32x16)0.0f;
                __builtin_amdgcn_s_setprio(1);
                #pragma unroll
                for (int ds = 0; ds < 4; ++ds) {
                    bf16x8 af = *(const bf16x8*)(kt2 + ((kg * 4 + ds) * 65 + lane) * 8);
                    s = __builtin_amdgcn_mfma_f32_32x32x16_bf16(af, qf[ds], s, 0, 0, 0);
                }
                __builtin_amdgcn_s_setprio(0);
                float lp = 0.0f;
                #pragma unroll
                for (int rp = 0; rp < 8; ++rp) {
                    float e0 = __builtin_amdgcn_exp2f(s[2 * rp]     - M0L2_);
                    float e1 = __builtin_amdgcn_exp2f(s[2 * rp + 1] - M0L2_);
                    if (diag) {
                        const int k0e = kti * 64 + kg * 32 + ((2 * rp) & 3) + 8 * ((2 * rp) >> 2) + 4 * hi;
                        if (k0e > qa)     e0 = 0.0f;
                        if (k0e + 1 > qa) e1 = 0.0f;   // reg 2rp+1 = key k0e+1
                    }
                    lp += e0 + e1;
                    wv[kg * 8 + rp] = cvt_pk_bf16(e0, e1);
                }
                l_acc += lp;
            }
            // PA frags: one swap fills two output words (guide §B recipe)
            bf16x8 pa[4];
            #pragma unroll
            for (int ks = 0; ks < 4; ++ks) {
                const int kg2 = ks >> 1, k1 = ks & 1;
                u32 x0 = wv[kg2 * 8 + k1 * 4 + 0], y0 = wv[kg2 * 8 + k1 * 4 + 2];
                u32 x1 = wv[kg2 * 8 + k1 * 4 + 1], y1 = wv[kg2 * 8 + k1 * 4 + 3];
                asm("v_permlane32_swap_b32 %0, %1" : "+v"(x0), "+v"(y0));
                asm("v_permlane32_swap_b32 %0, %1" : "+v"(x1), "+v"(y1));
                u32x4 t; t[0] = x0; t[1] = x1; t[2] = y0; t[3] = y1;
                pa[ks] = __builtin_bit_cast(bf16x8, t);
            }
            __builtin_amdgcn_s_setprio(1);
            #pragma unroll
            for (int ks = 0; ks < 4; ++ks) {
                bf16x8 vf0 = *(const bf16x8*)(vt2 + ((0 * 4 + ks) * 65 + lane) * 8);
                o0 = __builtin_amdgcn_mfma_f32_32x32x16_bf16(pa[ks], vf0, o0, 0, 0, 0);
                bf16x8 vf1 = *(const bf16x8*)(vt2 + ((1 * 4 + ks) * 65 + lane) * 8);
                o1 = __builtin_amdgcn_mfma_f32_32x32x16_bf16(pa[ks], vf1, o1, 0, 0, 0);
            }
            __builtin_amdgcn_s_setprio(0);
        }

        kti = kti_next;
        if (step < 3 && (i + 1) == bound) {   // q-tile crossing: flush + reset
            FLUSH(0);
            o0 = (f32x16)0.0f; o1 = (f32x16)0.0f; l_acc = 0.0f;
            qt = qtB; qrow0 = qt * 128 + w * 32;
            #pragma unroll
            for (int ds = 0; ds < 4; ++ds)
                qf[ds] = *(const bf16x8*)(qs + (base + qrow0 + l31) * HD_ + ds * 16 + hi * 8);
        }
    }
    FLUSH((t0 + 3 >= bound) ? 1 : 0);
}

// ---------------------------------------------------------------------------
// Kernel 3: merge partials. grid = (b, qt2, row-half) = 256 blocks.
// (unchanged from round 4 — verified)
// ---------------------------------------------------------------------------
__global__ __launch_bounds__(256) void merge_kernel(
    const float* __restrict__ pl, const u16* __restrict__ pO,
    float* __restrict__ out)
{
    const int bi  = blockIdx.x;            // b*64 + qt2*2 + rh
    const int rh  = bi & 1;
    const int qt2 = (bi >> 1) & 31;
    const int b   = bi >> 6;

    int c0, c1, role, mbase;
    if (qt2 <= 14)      { int u = qt2;      c0 = 0;                 c1 = (2 * u + 1) >> 2; role = 0; mbase = u * 16; }
    else if (qt2 == 15) { c0 = 0;           c1 = 7;                 role = 0; mbase = 240; }
    else if (qt2 <= 30) { int u = 30 - qt2; c0 = (2 * u + 2) >> 2;  c1 = 15; role = 1; mbase = u * 16; }
    else                { c0 = 0;           c1 = 15;                role = 0; mbase = 248; }

    const int row = rh * 64 + (threadIdx.x >> 2);
    const int hg  = (threadIdx.x & 3) * 16;

    float L = 0.0f;
    float o[16];
    #pragma unroll
    for (int i = 0; i < 16; ++i) o[i] = 0.0f;
    for (int c = c0; c <= c1; ++c) {
        const int slot = (b * CPB_ + mbase + c) * 2 + role;
        L += pl[slot * 128 + row];
        const u16* p = pO + (size_t)slot * 8192 + row * 64 + hg;
        bf16x8 v0 = *(const bf16x8*)p;
        bf16x8 v1 = *(const bf16x8*)(p + 8);
        #pragma unroll
        for (int i = 0; i < 8; ++i) { o[i] += bf2f((u16)v0[i]); o[8 + i] += bf2f((u16)v1[i]); }
    }
    const float inv = 1.0f / L;
    float* op = out + ((size_t)b * T_ + qt2 * 128 + row) * HD_ + hg;
    #pragma unroll
    for (int j = 0; j < 4; ++j) {
        f32x4 v;
        #pragma unroll
        for (int i = 0; i < 4; ++i) v[i] = o[j * 4 + i] * inv;
        *(f32x4*)(op + j * 4) = v;
    }
}

extern "C" void kernel_launch(void* const* d_in, const int* in_sizes, int n_in,
                              void* d_out, int out_size, void* d_ws, size_t ws_size,
                              hipStream_t stream) {
    const float* x  = (const float*)d_in[0];
    const float* wq = (const float*)d_in[1];
    const float* wk = (const float*)d_in[2];
    const float* wv = (const float*)d_in[3];

    const size_t NE = (size_t)BT_ * HD_;           // 1,048,576
    char* ws = (char*)d_ws;
    u16* qs   = (u16*)ws;                          // 2 MB (Q pre-scaled)
    u16* kss  = qs  + NE;                          // 2 MB
    u16* vssT = kss + NE;                          // 2 MB, [h][B*T]
    u16* wb   = vssT + NE;                         // 384 KB bf16 W (row-major)
    float* pl = (float*)(wb + 192 * 1024);         // NSLOT_*128 f32 = 1.08 MB
    u16* pO   = (u16*)(pl + (size_t)NSLOT_ * 128); // NSLOT_*8192 bf16 = 34.6 MB
    float* out = (float*)d_out;

    wconv_kernel<<<dim3(96),        dim3(256), 0, stream>>>(wq, wk, wv, wb);
    qkv_kernel  <<<dim3(256),       dim3(512), 0, stream>>>(x, wb, qs, kss, vssT);
    attn_kernel <<<dim3(4 * CPB_),  dim3(256), 0, stream>>>(qs, kss, vssT, pl, pO);
    merge_kernel<<<dim3(256),       dim3(256), 0, stream>>>(pl, pO, out);
}

// Round 9
// 146.291 us; speedup vs baseline: 1.1677x; 1.0010x over previous
//
#include <hip/hip_runtime.h>
#include <stdint.h>

#define B_  4
#define T_  4096
#define D_  1024
#define HD_ 64
#define BT_ 16384   // B_*T_

typedef short bf16x8 __attribute__((ext_vector_type(8)));
typedef float f32x4  __attribute__((ext_vector_type(4)));
typedef float f32x16 __attribute__((ext_vector_type(16)));
typedef unsigned short u16;
typedef u16 u16x4 __attribute__((ext_vector_type(4)));
typedef unsigned int u32;
typedef u32 u32x4 __attribute__((ext_vector_type(4)));

#define M0L2_  11.54156032f  // M0(=8) * log2(e)
#define QSCALE_ 0.18033688f  // 0.125 * log2(e): folds softmax scale AND exp2 base

#define CPB_   264           // chunks (=attn blocks) per batch, 4 tile-tasks each
#define NSLOT_ (4 * CPB_ * 2)

__device__ __forceinline__ u16 f2bf(float f) {
    union { float f; unsigned u; } v; v.f = f;
    unsigned r = (v.u + 0x7FFF + ((v.u >> 16) & 1)) >> 16;
    return (u16)r;
}
__device__ __forceinline__ float bf2f(u16 u) {
    union { unsigned u; float f; } v; v.u = ((unsigned)u) << 16;
    return v.f;
}
// packed f32x2 -> bf16x2 (lo = first operand)
__device__ __forceinline__ u32 cvt_pk_bf16(float lo, float hi) {
    u32 r;
    asm("v_cvt_pk_bf16_f32 %0, %1, %2" : "=v"(r) : "v"(lo), "v"(hi));
    return r;
}

// ---------------------------------------------------------------------------
// Kernel 0: W fp32 -> packed bf16 [192][1024] row-major (rows 0-63 Wq,
// 64-127 Wk, 128-191 Wv).
// ---------------------------------------------------------------------------
__global__ __launch_bounds__(256) void wconv_kernel(
    const float* __restrict__ wq, const float* __restrict__ wk,
    const float* __restrict__ wv, u16* __restrict__ wb)
{
    const int j   = blockIdx.x >> 5;
    const int off = (blockIdx.x & 31) * 2048 + threadIdx.x * 8;
    const float* src = (j == 0) ? wq : ((j == 1) ? wk : wv);
    f32x4 a0 = *(const f32x4*)(src + off);
    f32x4 a1 = *(const f32x4*)(src + off + 4);
    u32x4 b;
    b[0] = cvt_pk_bf16(a0[0], a0[1]);
    b[1] = cvt_pk_bf16(a0[2], a0[3]);
    b[2] = cvt_pk_bf16(a1[0], a1[1]);
    b[3] = cvt_pk_bf16(a1[2], a1[3]);
    *(u32x4*)(wb + j * 65536 + off) = b;
}

// ---------------------------------------------------------------------------
// Kernel 1: QKV projection — 64-row tiles, 512 threads, double-buffered LDS,
// PREFETCH DISTANCE 2. Rounds 1/4/7/8 all land at 32-34 us across very
// different LDS ledgers => LDS is not the bottleneck; the invariant is x
// arriving COLD from HBM (the 268 MB workspace poison evicts L3 every
// iteration) with only 1-tile lookahead: each kc exposes ~500+ cy of HBM
// latency at the pre-barrier vmcnt drain. Fix: regs written to LDS at iter
// kc were loaded at iter kc-1; iter kc issues loads for tile kc+2. Two
// NAMED register sets A/B (rule: no runtime-indexed register arrays).
// Emits: qs[row][h] (x 0.125*log2e), kss[row][h], vssT[h][row] (transposed).
// ---------------------------------------------------------------------------
struct StageSet { f32x4 xa, xb; bf16x8 w0, w1, w2; };

__global__ __launch_bounds__(512, 2) void qkv_kernel(
    const float* __restrict__ x, const u16* __restrict__ wb,
    u16* __restrict__ qs, u16* __restrict__ kss, u16* __restrict__ vssT)
{
    __shared__ __align__(16) u16 xt[2][64][72];
    __shared__ __align__(16) u16 wt[2][192][72];

    const int tid  = threadIdx.x;
    const int lane = tid & 63;
    const int w    = tid >> 6;          // 0..7
    const int quad = lane >> 4;
    const int l16  = lane & 15;
    const int row0 = blockIdx.x * 64;
    const int rh   = w >> 2;            // row-half (32 rows)
    const int ct   = w & 3;             // col-triple (3 col-groups of 16)

    const int xrow = tid >> 3;          // 0..63  (x staging row)
    const int xcg  = tid & 7;           // col-group *8

    f32x4 acc[2][3];
    #pragma unroll
    for (int s = 0; s < 2; ++s)
        #pragma unroll
        for (int g = 0; g < 3; ++g) acc[s][g] = (f32x4)0.0f;

    const float* xbase = x + (size_t)(row0 + xrow) * D_ + xcg * 8;
    const int    wrow  = tid >> 3;      // reuse: chunk geometry below

    auto load_tile = [&](StageSet& S, int t) {
        const float* xp = xbase + t * 64;
        S.xa = *(const f32x4*)xp; S.xb = *(const f32x4*)(xp + 4);
        const u16* wp = wb + t * 64;
        S.w0 = *(const bf16x8*)(wp + (size_t)((tid       ) >> 3) * D_ + ((tid       ) & 7) * 8);
        S.w1 = *(const bf16x8*)(wp + (size_t)((tid +  512) >> 3) * D_ + ((tid +  512) & 7) * 8);
        S.w2 = *(const bf16x8*)(wp + (size_t)((tid + 1024) >> 3) * D_ + ((tid + 1024) & 7) * 8);
    };
    auto store_tile = [&](const StageSet& S, int bufi) {
        u32x4 px;
        px[0] = cvt_pk_bf16(S.xa[0], S.xa[1]);
        px[1] = cvt_pk_bf16(S.xa[2], S.xa[3]);
        px[2] = cvt_pk_bf16(S.xb[0], S.xb[1]);
        px[3] = cvt_pk_bf16(S.xb[2], S.xb[3]);
        *(u32x4*)&xt[bufi][xrow][xcg * 8] = px;
        *(bf16x8*)&wt[bufi][(tid       ) >> 3][((tid       ) & 7) * 8] = S.w0;
        *(bf16x8*)&wt[bufi][(tid +  512) >> 3][((tid +  512) & 7) * 8] = S.w1;
        *(bf16x8*)&wt[bufi][(tid + 1024) >> 3][((tid + 1024) & 7) * 8] = S.w2;
    };
    auto compute = [&](int bufi) {
        #pragma unroll
        for (int ks = 0; ks < 2; ++ks) {
            bf16x8 a[2];
            #pragma unroll
            for (int s = 0; s < 2; ++s)
                a[s] = *(const bf16x8*)&xt[bufi][rh * 32 + s * 16 + l16][ks * 32 + quad * 8];
            #pragma unroll
            for (int g = 0; g < 3; ++g) {
                bf16x8 bfr = *(const bf16x8*)&wt[bufi][(ct * 3 + g) * 16 + l16][ks * 32 + quad * 8];
                #pragma unroll
                for (int s = 0; s < 2; ++s)
                    acc[s][g] = __builtin_amdgcn_mfma_f32_16x16x32_bf16(a[s], bfr, acc[s][g], 0, 0, 0);
            }
        }
    };

    StageSet A, B;
    load_tile(A, 0);                    // tile 0
    load_tile(B, 1);                    // tile 1 (in flight through iter 0)
    store_tile(A, 0);
    __syncthreads();

    #pragma unroll
    for (int kc2 = 0; kc2 < 8; ++kc2) {
        const int kc = kc2 * 2;
        // even kc: compute buf0 (tile kc); write tile kc+1 (set B, loaded kc-1);
        //          issue loads for tile kc+2 into set A (its tile was consumed)
        if (kc + 2 < 16) load_tile(A, kc + 2);
        compute(0);
        store_tile(B, 1);               // tile kc+1 -> buf1 (kc+1 <= 15 always here)
        __syncthreads();
        // odd kc+1: compute buf1 (tile kc+1); write tile kc+2 (set A); load kc+3 -> B
        if (kc + 3 < 16) load_tile(B, kc + 3);
        compute(1);
        if (kc + 2 < 16) store_tile(A, 0);
        __syncthreads();
    }

    // epilogue: C/D layout row=quad*4+r, col=l16
    #pragma unroll
    for (int s = 0; s < 2; ++s) {
        #pragma unroll
        for (int g = 0; g < 3; ++g) {
            const int n = (ct * 3 + g) * 16 + l16;
            const int j = n >> 6, h = n & 63;
            const int rbase = row0 + rh * 32 + s * 16 + quad * 4;
            if (j == 0) {
                #pragma unroll
                for (int r = 0; r < 4; ++r) qs[(size_t)(rbase + r) * HD_ + h] = f2bf(acc[s][g][r] * QSCALE_);
            } else if (j == 1) {
                #pragma unroll
                for (int r = 0; r < 4; ++r) kss[(size_t)(rbase + r) * HD_ + h] = f2bf(acc[s][g][r]);
            } else {
                u16x4 v;
                #pragma unroll
                for (int r = 0; r < 4; ++r) v[r] = f2bf(acc[s][g][r]);
                *(u16x4*)(vssT + (size_t)h * BT_ + rbase) = v;   // transposed store
            }
        }
    }
}

// ---------------------------------------------------------------------------
// Kernel 2: flash attention, 32x32 swapped-QK, P fully in registers.
// (unchanged from round 4 — verified)
// ---------------------------------------------------------------------------
__global__ __launch_bounds__(256, 4) void attn_kernel(
    const u16* __restrict__ qs, const u16* __restrict__ kss,
    const u16* __restrict__ vssT,
    float* __restrict__ pl, u16* __restrict__ pO)
{
    __shared__ __align__(16) u16 kt2[8 * 65 * 8];
    __shared__ __align__(16) u16 vt2[8 * 65 * 8];

    const int m = blockIdx.x % CPB_;
    const int b = blockIdx.x / CPB_;

    int t0, bound, qtA, qtB;
    if (m < 240)      { int u = m >> 4; t0 = (m & 15) * 4; bound = 2 * u + 2; qtA = u;  qtB = 30 - u; }
    else if (m < 248) { t0 = (m - 240) * 4; bound = 1 << 30; qtA = 15; qtB = 15; }
    else              { t0 = (m - 248) * 4; bound = 1 << 30; qtA = 31; qtB = 31; }

    const int tid  = threadIdx.x;
    const int lane = tid & 63;
    const int w    = tid >> 6;
    const int l31  = lane & 31;
    const int hi   = lane >> 5;
    const size_t base = (size_t)b * T_;

    int qt    = (t0 < bound) ? qtA : qtB;
    int kti   = (t0 < bound) ? t0 : (t0 - bound);
    int qrow0 = qt * 128 + w * 32;

    // Q B-frags: lane holds Q[q=l31][ds*16 + hi*8 + 0..7]
    bf16x8 qf[4];
    #pragma unroll
    for (int ds = 0; ds < 4; ++ds)
        qf[ds] = *(const bf16x8*)(qs + (base + qrow0 + l31) * HD_ + ds * 16 + hi * 8);

    f32x16 o0 = (f32x16)0.0f, o1 = (f32x16)0.0f;
    float l_acc = 0.0f;

    // staging: thread t -> row t>>2 (key for K / d for V), 32B at col (t&3)*16
    const int srow = tid >> 2, q4 = tid & 3;
    const u16* kp = kss  + (base + srow) * HD_ + q4 * 16;
    const u16* vp = vssT + (size_t)srow * BT_ + base + q4 * 16;
    u16* kdst = kt2 + ((((srow >> 5) * 4 + q4) * 65 + (srow & 31)) * 8);
    u16* vdst = vt2 + ((((srow >> 5) * 4 + q4) * 65 + (srow & 31)) * 8);

    bf16x8 kr0, kr1, vr0, vr1;
    {
        const u16* k0 = kp + (size_t)kti * 64 * HD_;
        kr0 = *(const bf16x8*)k0; kr1 = *(const bf16x8*)(k0 + 8);
        const u16* v0 = vp + kti * 64;
        vr0 = *(const bf16x8*)v0; vr1 = *(const bf16x8*)(v0 + 8);
    }

    auto FLUSH = [&](int role) {
        const int slot = (b * CPB_ + m) * 2 + role;
        u32 la = __builtin_bit_cast(u32, l_acc), lb = la;
        asm("v_permlane32_swap_b32 %0, %1" : "+v"(la), "+v"(lb));
        float lfull = __builtin_bit_cast(float, la) + __builtin_bit_cast(float, lb);
        if (hi == 0) pl[slot * 128 + w * 32 + l31] = lfull;
        #pragma unroll
        for (int reg = 0; reg < 16; ++reg) {
            int row = w * 32 + (reg & 3) + 8 * (reg >> 2) + 4 * hi;
            pO[(size_t)slot * 8192 + row * 64 + l31]      = f2bf(o0[reg]);
            pO[(size_t)slot * 8192 + row * 64 + 32 + l31] = f2bf(o1[reg]);
        }
    };

    for (int step = 0; step < 4; ++step) {
        const int i = t0 + step;
        __syncthreads();
        *(bf16x8*)(kdst)       = kr0;
        *(bf16x8*)(kdst + 256) = kr1;
        *(bf16x8*)(vdst)       = vr0;
        *(bf16x8*)(vdst + 256) = vr1;
        __syncthreads();

        int kti_next = 0;
        if (step < 3) {
            kti_next = (i + 1 < bound) ? (i + 1) : (i + 1 - bound);
            const u16* k0 = kp + (size_t)kti_next * 64 * HD_;
            kr0 = *(const bf16x8*)k0; kr1 = *(const bf16x8*)(k0 + 8);
            const u16* v0 = vp + kti_next * 64;
            vr0 = *(const bf16x8*)v0; vr1 = *(const bf16x8*)(v0 + 8);
        }

        if (kti * 64 <= qrow0 + 31) {      // warp-uniform skip of fully-masked tiles
            const bool diag = (kti * 64 + 63 > qrow0);
            const int  qa   = qrow0 + l31;
            u32 wv[16];
            #pragma unroll
            for (int kg = 0; kg < 2; ++kg) {
                f32x16 s = (f32x16)0.0f;
                __builtin_amdgcn_s_setprio(1);
                #pragma unroll
                for (int ds = 0; ds < 4; ++ds) {
                    bf16x8 af = *(const bf16x8*)(kt2 + ((kg * 4 + ds) * 65 + lane) * 8);
                    s = __builtin_amdgcn_mfma_f32_32x32x16_bf16(af, qf[ds], s, 0, 0, 0);
                }
                __builtin_amdgcn_s_setprio(0);
                float lp = 0.0f;
                #pragma unroll
                for (int rp = 0; rp < 8; ++rp) {
                    float e0 = __builtin_amdgcn_exp2f(s[2 * rp]     - M0L2_);
                    float e1 = __builtin_amdgcn_exp2f(s[2 * rp + 1] - M0L2_);
                    if (diag) {
                        const int k0e = kti * 64 + kg * 32 + ((2 * rp) & 3) + 8 * ((2 * rp) >> 2) + 4 * hi;
                        if (k0e > qa)     e0 = 0.0f;
                        if (k0e + 1 > qa) e1 = 0.0f;   // reg 2rp+1 = key k0e+1
                    }
                    lp += e0 + e1;
                    wv[kg * 8 + rp] = cvt_pk_bf16(e0, e1);
                }
                l_acc += lp;
            }
            // PA frags: one swap fills two output words (guide §B recipe)
            bf16x8 pa[4];
            #pragma unroll
            for (int ks = 0; ks < 4; ++ks) {
                const int kg2 = ks >> 1, k1 = ks & 1;
                u32 x0 = wv[kg2 * 8 + k1 * 4 + 0], y0 = wv[kg2 * 8 + k1 * 4 + 2];
                u32 x1 = wv[kg2 * 8 + k1 * 4 + 1], y1 = wv[kg2 * 8 + k1 * 4 + 3];
                asm("v_permlane32_swap_b32 %0, %1" : "+v"(x0), "+v"(y0));
                asm("v_permlane32_swap_b32 %0, %1" : "+v"(x1), "+v"(y1));
                u32x4 t; t[0] = x0; t[1] = x1; t[2] = y0; t[3] = y1;
                pa[ks] = __builtin_bit_cast(bf16x8, t);
            }
            __builtin_amdgcn_s_setprio(1);
            #pragma unroll
            for (int ks = 0; ks < 4; ++ks) {
                bf16x8 vf0 = *(const bf16x8*)(vt2 + ((0 * 4 + ks) * 65 + lane) * 8);
                o0 = __builtin_amdgcn_mfma_f32_32x32x16_bf16(pa[ks], vf0, o0, 0, 0, 0);
                bf16x8 vf1 = *(const bf16x8*)(vt2 + ((1 * 4 + ks) * 65 + lane) * 8);
                o1 = __builtin_amdgcn_mfma_f32_32x32x16_bf16(pa[ks], vf1, o1, 0, 0, 0);
            }
            __builtin_amdgcn_s_setprio(0);
        }

        kti = kti_next;
        if (step < 3 && (i + 1) == bound) {   // q-tile crossing: flush + reset
            FLUSH(0);
            o0 = (f32x16)0.0f; o1 = (f32x16)0.0f; l_acc = 0.0f;
            qt = qtB; qrow0 = qt * 128 + w * 32;
            #pragma unroll
            for (int ds = 0; ds < 4; ++ds)
                qf[ds] = *(const bf16x8*)(qs + (base + qrow0 + l31) * HD_ + ds * 16 + hi * 8);
        }
    }
    FLUSH((t0 + 3 >= bound) ? 1 : 0);
}

// ---------------------------------------------------------------------------
// Kernel 3: merge partials. grid = (b, qt2, row-half) = 256 blocks.
// (unchanged from round 4 — verified)
// ---------------------------------------------------------------------------
__global__ __launch_bounds__(256) void merge_kernel(
    const float* __restrict__ pl, const u16* __restrict__ pO,
    float* __restrict__ out)
{
    const int bi  = blockIdx.x;            // b*64 + qt2*2 + rh
    const int rh  = bi & 1;
    const int qt2 = (bi >> 1) & 31;
    const int b   = bi >> 6;

    int c0, c1, role, mbase;
    if (qt2 <= 14)      { int u = qt2;      c0 = 0;                 c1 = (2 * u + 1) >> 2; role = 0; mbase = u * 16; }
    else if (qt2 == 15) { c0 = 0;           c1 = 7;                 role = 0; mbase = 240; }
    else if (qt2 <= 30) { int u = 30 - qt2; c0 = (2 * u + 2) >> 2;  c1 = 15; role = 1; mbase = u * 16; }
    else                { c0 = 0;           c1 = 15;                role = 0; mbase = 248; }

    const int row = rh * 64 + (threadIdx.x >> 2);
    const int hg  = (threadIdx.x & 3) * 16;

    float L = 0.0f;
    float o[16];
    #pragma unroll
    for (int i = 0; i < 16; ++i) o[i] = 0.0f;
    for (int c = c0; c <= c1; ++c) {
        const int slot = (b * CPB_ + mbase + c) * 2 + role;
        L += pl[slot * 128 + row];
        const u16* p = pO + (size_t)slot * 8192 + row * 64 + hg;
        bf16x8 v0 = *(const bf16x8*)p;
        bf16x8 v1 = *(const bf16x8*)(p + 8);
        #pragma unroll
        for (int i = 0; i < 8; ++i) { o[i] += bf2f((u16)v0[i]); o[8 + i] += bf2f((u16)v1[i]); }
    }
    const float inv = 1.0f / L;
    float* op = out + ((size_t)b * T_ + qt2 * 128 + row) * HD_ + hg;
    #pragma unroll
    for (int j = 0; j < 4; ++j) {
        f32x4 v;
        #pragma unroll
        for (int i = 0; i < 4; ++i) v[i] = o[j * 4 + i] * inv;
        *(f32x4*)(op + j * 4) = v;
    }
}

extern "C" void kernel_launch(void* const* d_in, const int* in_sizes, int n_in,
                              void* d_out, int out_size, void* d_ws, size_t ws_size,
                              hipStream_t stream) {
    const float* x  = (const float*)d_in[0];
    const float* wq = (const float*)d_in[1];
    const float* wk = (const float*)d_in[2];
    const float* wv = (const float*)d_in[3];

    const size_t NE = (size_t)BT_ * HD_;           // 1,048,576
    char* ws = (char*)d_ws;
    u16* qs   = (u16*)ws;                          // 2 MB (Q pre-scaled)
    u16* kss  = qs  + NE;                          // 2 MB
    u16* vssT = kss + NE;                          // 2 MB, [h][B*T]
    u16* wb   = vssT + NE;                         // 384 KB bf16 W (row-major)
    float* pl = (float*)(wb + 192 * 1024);         // NSLOT_*128 f32 = 1.08 MB
    u16* pO   = (u16*)(pl + (size_t)NSLOT_ * 128); // NSLOT_*8192 bf16 = 34.6 MB
    float* out = (float*)d_out;

    wconv_kernel<<<dim3(96),        dim3(256), 0, stream>>>(wq, wk, wv, wb);
    qkv_kernel  <<<dim3(256),       dim3(512), 0, stream>>>(x, wb, qs, kss, vssT);
    attn_kernel <<<dim3(4 * CPB_),  dim3(256), 0, stream>>>(qs, kss, vssT, pl, pO);
    merge_kernel<<<dim3(256),       dim3(256), 0, stream>>>(pl, pO, out);
}

// Round 10
// 146.108 us; speedup vs baseline: 1.1691x; 1.0013x over previous
//
#include <hip/hip_runtime.h>
#include <stdint.h>

#define B_  4
#define T_  4096
#define D_  1024
#define HD_ 64
#define BT_ 16384   // B_*T_

typedef short bf16x8 __attribute__((ext_vector_type(8)));
typedef float f32x4  __attribute__((ext_vector_type(4)));
typedef float f32x16 __attribute__((ext_vector_type(16)));
typedef unsigned short u16;
typedef u16 u16x4 __attribute__((ext_vector_type(4)));
typedef unsigned int u32;
typedef u32 u32x4 __attribute__((ext_vector_type(4)));

#define M0L2_  11.54156032f  // M0(=8) * log2(e)
#define QSCALE_ 0.18033688f  // 0.125 * log2(e): folds softmax scale AND exp2 base

#define CPB_   132           // chunks (=attn blocks) per batch, 8 tile-tasks each
#define NSLOT_ (4 * CPB_ * 2)

__device__ __forceinline__ u16 f2bf(float f) {
    union { float f; unsigned u; } v; v.f = f;
    unsigned r = (v.u + 0x7FFF + ((v.u >> 16) & 1)) >> 16;
    return (u16)r;
}
__device__ __forceinline__ float bf2f(u16 u) {
    union { unsigned u; float f; } v; v.u = ((unsigned)u) << 16;
    return v.f;
}
// packed f32x2 -> bf16x2 (lo = first operand)
__device__ __forceinline__ u32 cvt_pk_bf16(float lo, float hi) {
    u32 r;
    asm("v_cvt_pk_bf16_f32 %0, %1, %2" : "=v"(r) : "v"(lo), "v"(hi));
    return r;
}

// ---------------------------------------------------------------------------
// Kernel 0: W fp32 -> packed bf16 [192][1024] row-major (rows 0-63 Wq,
// 64-127 Wk, 128-191 Wv).
// ---------------------------------------------------------------------------
__global__ __launch_bounds__(256) void wconv_kernel(
    const float* __restrict__ wq, const float* __restrict__ wk,
    const float* __restrict__ wv, u16* __restrict__ wb)
{
    const int j   = blockIdx.x >> 5;
    const int off = (blockIdx.x & 31) * 2048 + threadIdx.x * 8;
    const float* src = (j == 0) ? wq : ((j == 1) ? wk : wv);
    f32x4 a0 = *(const f32x4*)(src + off);
    f32x4 a1 = *(const f32x4*)(src + off + 4);
    u32x4 b;
    b[0] = cvt_pk_bf16(a0[0], a0[1]);
    b[1] = cvt_pk_bf16(a0[2], a0[3]);
    b[2] = cvt_pk_bf16(a1[0], a1[1]);
    b[3] = cvt_pk_bf16(a1[2], a1[3]);
    *(u32x4*)(wb + j * 65536 + off) = b;
}

// ---------------------------------------------------------------------------
// Kernel 1: QKV projection — 64-row tiles, 512 threads, double-buffered LDS,
// prefetch distance 2. (unchanged from round 9; qkv has tied at ~32 us
// across 4 structural variants — treated as floor pending direct profile)
// ---------------------------------------------------------------------------
struct StageSet { f32x4 xa, xb; bf16x8 w0, w1, w2; };

__global__ __launch_bounds__(512, 2) void qkv_kernel(
    const float* __restrict__ x, const u16* __restrict__ wb,
    u16* __restrict__ qs, u16* __restrict__ kss, u16* __restrict__ vssT)
{
    __shared__ __align__(16) u16 xt[2][64][72];
    __shared__ __align__(16) u16 wt[2][192][72];

    const int tid  = threadIdx.x;
    const int lane = tid & 63;
    const int w    = tid >> 6;          // 0..7
    const int quad = lane >> 4;
    const int l16  = lane & 15;
    const int row0 = blockIdx.x * 64;
    const int rh   = w >> 2;            // row-half (32 rows)
    const int ct   = w & 3;             // col-triple (3 col-groups of 16)

    const int xrow = tid >> 3;          // 0..63  (x staging row)
    const int xcg  = tid & 7;           // col-group *8

    f32x4 acc[2][3];
    #pragma unroll
    for (int s = 0; s < 2; ++s)
        #pragma unroll
        for (int g = 0; g < 3; ++g) acc[s][g] = (f32x4)0.0f;

    const float* xbase = x + (size_t)(row0 + xrow) * D_ + xcg * 8;

    auto load_tile = [&](StageSet& S, int t) {
        const float* xp = xbase + t * 64;
        S.xa = *(const f32x4*)xp; S.xb = *(const f32x4*)(xp + 4);
        const u16* wp = wb + t * 64;
        S.w0 = *(const bf16x8*)(wp + (size_t)((tid       ) >> 3) * D_ + ((tid       ) & 7) * 8);
        S.w1 = *(const bf16x8*)(wp + (size_t)((tid +  512) >> 3) * D_ + ((tid +  512) & 7) * 8);
        S.w2 = *(const bf16x8*)(wp + (size_t)((tid + 1024) >> 3) * D_ + ((tid + 1024) & 7) * 8);
    };
    auto store_tile = [&](const StageSet& S, int bufi) {
        u32x4 px;
        px[0] = cvt_pk_bf16(S.xa[0], S.xa[1]);
        px[1] = cvt_pk_bf16(S.xa[2], S.xa[3]);
        px[2] = cvt_pk_bf16(S.xb[0], S.xb[1]);
        px[3] = cvt_pk_bf16(S.xb[2], S.xb[3]);
        *(u32x4*)&xt[bufi][xrow][xcg * 8] = px;
        *(bf16x8*)&wt[bufi][(tid       ) >> 3][((tid       ) & 7) * 8] = S.w0;
        *(bf16x8*)&wt[bufi][(tid +  512) >> 3][((tid +  512) & 7) * 8] = S.w1;
        *(bf16x8*)&wt[bufi][(tid + 1024) >> 3][((tid + 1024) & 7) * 8] = S.w2;
    };
    auto compute = [&](int bufi) {
        #pragma unroll
        for (int ks = 0; ks < 2; ++ks) {
            bf16x8 a[2];
            #pragma unroll
            for (int s = 0; s < 2; ++s)
                a[s] = *(const bf16x8*)&xt[bufi][rh * 32 + s * 16 + l16][ks * 32 + quad * 8];
            #pragma unroll
            for (int g = 0; g < 3; ++g) {
                bf16x8 bfr = *(const bf16x8*)&wt[bufi][(ct * 3 + g) * 16 + l16][ks * 32 + quad * 8];
                #pragma unroll
                for (int s = 0; s < 2; ++s)
                    acc[s][g] = __builtin_amdgcn_mfma_f32_16x16x32_bf16(a[s], bfr, acc[s][g], 0, 0, 0);
            }
        }
    };

    StageSet A, B;
    load_tile(A, 0);                    // tile 0
    load_tile(B, 1);                    // tile 1 (in flight through iter 0)
    store_tile(A, 0);
    __syncthreads();

    #pragma unroll
    for (int kc2 = 0; kc2 < 8; ++kc2) {
        const int kc = kc2 * 2;
        if (kc + 2 < 16) load_tile(A, kc + 2);
        compute(0);
        store_tile(B, 1);
        __syncthreads();
        if (kc + 3 < 16) load_tile(B, kc + 3);
        compute(1);
        if (kc + 2 < 16) store_tile(A, 0);
        __syncthreads();
    }

    // epilogue: C/D layout row=quad*4+r, col=l16
    #pragma unroll
    for (int s = 0; s < 2; ++s) {
        #pragma unroll
        for (int g = 0; g < 3; ++g) {
            const int n = (ct * 3 + g) * 16 + l16;
            const int j = n >> 6, h = n & 63;
            const int rbase = row0 + rh * 32 + s * 16 + quad * 4;
            if (j == 0) {
                #pragma unroll
                for (int r = 0; r < 4; ++r) qs[(size_t)(rbase + r) * HD_ + h] = f2bf(acc[s][g][r] * QSCALE_);
            } else if (j == 1) {
                #pragma unroll
                for (int r = 0; r < 4; ++r) kss[(size_t)(rbase + r) * HD_ + h] = f2bf(acc[s][g][r]);
            } else {
                u16x4 v;
                #pragma unroll
                for (int r = 0; r < 4; ++r) v[r] = f2bf(acc[s][g][r]);
                *(u16x4*)(vssT + (size_t)h * BT_ + rbase) = v;   // transposed store
            }
        }
    }
}

// ---------------------------------------------------------------------------
// Kernel 2: flash attention, 32x32 swapped-QK, P fully in registers.
// CHUNK = 8 tasks/block (was 4): 132 chunks/batch, 528 blocks, 8 steps each.
// Halves pO write traffic (34.6 -> 17.3 MB) and FLUSH epilogues; merge reads
// halve. Pairing u<->30-u gives 64 tasks = 8 chunks; qt2=15 standalone 4
// chunks; qt2=31 standalone 8 chunks. At most one q-tile crossing per block.
// ---------------------------------------------------------------------------
__global__ __launch_bounds__(256, 4) void attn_kernel(
    const u16* __restrict__ qs, const u16* __restrict__ kss,
    const u16* __restrict__ vssT,
    float* __restrict__ pl, u16* __restrict__ pO)
{
    __shared__ __align__(16) u16 kt2[8 * 65 * 8];
    __shared__ __align__(16) u16 vt2[8 * 65 * 8];

    const int m = blockIdx.x % CPB_;
    const int b = blockIdx.x / CPB_;

    int t0, bound, qtA, qtB;
    if (m < 120)      { int u = m >> 3; t0 = (m & 7) * 8; bound = 2 * u + 2; qtA = u;  qtB = 30 - u; }
    else if (m < 124) { t0 = (m - 120) * 8; bound = 1 << 30; qtA = 15; qtB = 15; }
    else              { t0 = (m - 124) * 8; bound = 1 << 30; qtA = 31; qtB = 31; }

    const int tid  = threadIdx.x;
    const int lane = tid & 63;
    const int w    = tid >> 6;
    const int l31  = lane & 31;
    const int hi   = lane >> 5;
    const size_t base = (size_t)b * T_;

    int qt    = (t0 < bound) ? qtA : qtB;
    int kti   = (t0 < bound) ? t0 : (t0 - bound);
    int qrow0 = qt * 128 + w * 32;

    // Q B-frags: lane holds Q[q=l31][ds*16 + hi*8 + 0..7]
    bf16x8 qf[4];
    #pragma unroll
    for (int ds = 0; ds < 4; ++ds)
        qf[ds] = *(const bf16x8*)(qs + (base + qrow0 + l31) * HD_ + ds * 16 + hi * 8);

    f32x16 o0 = (f32x16)0.0f, o1 = (f32x16)0.0f;
    float l_acc = 0.0f;

    // staging: thread t -> row t>>2 (key for K / d for V), 32B at col (t&3)*16
    const int srow = tid >> 2, q4 = tid & 3;
    const u16* kp = kss  + (base + srow) * HD_ + q4 * 16;
    const u16* vp = vssT + (size_t)srow * BT_ + base + q4 * 16;
    u16* kdst = kt2 + ((((srow >> 5) * 4 + q4) * 65 + (srow & 31)) * 8);
    u16* vdst = vt2 + ((((srow >> 5) * 4 + q4) * 65 + (srow & 31)) * 8);

    bf16x8 kr0, kr1, vr0, vr1;
    {
        const u16* k0 = kp + (size_t)kti * 64 * HD_;
        kr0 = *(const bf16x8*)k0; kr1 = *(const bf16x8*)(k0 + 8);
        const u16* v0 = vp + kti * 64;
        vr0 = *(const bf16x8*)v0; vr1 = *(const bf16x8*)(v0 + 8);
    }

    auto FLUSH = [&](int role) {
        const int slot = (b * CPB_ + m) * 2 + role;
        u32 la = __builtin_bit_cast(u32, l_acc), lb = la;
        asm("v_permlane32_swap_b32 %0, %1" : "+v"(la), "+v"(lb));
        float lfull = __builtin_bit_cast(float, la) + __builtin_bit_cast(float, lb);
        if (hi == 0) pl[slot * 128 + w * 32 + l31] = lfull;
        #pragma unroll
        for (int reg = 0; reg < 16; ++reg) {
            int row = w * 32 + (reg & 3) + 8 * (reg >> 2) + 4 * hi;
            pO[(size_t)slot * 8192 + row * 64 + l31]      = f2bf(o0[reg]);
            pO[(size_t)slot * 8192 + row * 64 + 32 + l31] = f2bf(o1[reg]);
        }
    };

    for (int step = 0; step < 8; ++step) {
        const int i = t0 + step;
        __syncthreads();
        *(bf16x8*)(kdst)       = kr0;
        *(bf16x8*)(kdst + 256) = kr1;
        *(bf16x8*)(vdst)       = vr0;
        *(bf16x8*)(vdst + 256) = vr1;
        __syncthreads();

        int kti_next = 0;
        if (step < 7) {
            kti_next = (i + 1 < bound) ? (i + 1) : (i + 1 - bound);
            const u16* k0 = kp + (size_t)kti_next * 64 * HD_;
            kr0 = *(const bf16x8*)k0; kr1 = *(const bf16x8*)(k0 + 8);
            const u16* v0 = vp + kti_next * 64;
            vr0 = *(const bf16x8*)v0; vr1 = *(const bf16x8*)(v0 + 8);
        }

        if (kti * 64 <= qrow0 + 31) {      // warp-uniform skip of fully-masked tiles
            const bool diag = (kti * 64 + 63 > qrow0);
            const int  qa   = qrow0 + l31;
            u32 wv[16];
            #pragma unroll
            for (int kg = 0; kg < 2; ++kg) {
                f32x16 s = (f32x16)0.0f;
                __builtin_amdgcn_s_setprio(1);
                #pragma unroll
                for (int ds = 0; ds < 4; ++ds) {
                    bf16x8 af = *(const bf16x8*)(kt2 + ((kg * 4 + ds) * 65 + lane) * 8);
                    s = __builtin_amdgcn_mfma_f32_32x32x16_bf16(af, qf[ds], s, 0, 0, 0);
                }
                __builtin_amdgcn_s_setprio(0);
                float lp = 0.0f;
                #pragma unroll
                for (int rp = 0; rp < 8; ++rp) {
                    float e0 = __builtin_amdgcn_exp2f(s[2 * rp]     - M0L2_);
                    float e1 = __builtin_amdgcn_exp2f(s[2 * rp + 1] - M0L2_);
                    if (diag) {
                        const int k0e = kti * 64 + kg * 32 + ((2 * rp) & 3) + 8 * ((2 * rp) >> 2) + 4 * hi;
                        if (k0e > qa)     e0 = 0.0f;
                        if (k0e + 1 > qa) e1 = 0.0f;   // reg 2rp+1 = key k0e+1
                    }
                    lp += e0 + e1;
                    wv[kg * 8 + rp] = cvt_pk_bf16(e0, e1);
                }
                l_acc += lp;
            }
            // PA frags: one swap fills two output words (guide §B recipe)
            bf16x8 pa[4];
            #pragma unroll
            for (int ks = 0; ks < 4; ++ks) {
                const int kg2 = ks >> 1, k1 = ks & 1;
                u32 x0 = wv[kg2 * 8 + k1 * 4 + 0], y0 = wv[kg2 * 8 + k1 * 4 + 2];
                u32 x1 = wv[kg2 * 8 + k1 * 4 + 1], y1 = wv[kg2 * 8 + k1 * 4 + 3];
                asm("v_permlane32_swap_b32 %0, %1" : "+v"(x0), "+v"(y0));
                asm("v_permlane32_swap_b32 %0, %1" : "+v"(x1), "+v"(y1));
                u32x4 t; t[0] = x0; t[1] = x1; t[2] = y0; t[3] = y1;
                pa[ks] = __builtin_bit_cast(bf16x8, t);
            }
            __builtin_amdgcn_s_setprio(1);
            #pragma unroll
            for (int ks = 0; ks < 4; ++ks) {
                bf16x8 vf0 = *(const bf16x8*)(vt2 + ((0 * 4 + ks) * 65 + lane) * 8);
                o0 = __builtin_amdgcn_mfma_f32_32x32x16_bf16(pa[ks], vf0, o0, 0, 0, 0);
                bf16x8 vf1 = *(const bf16x8*)(vt2 + ((1 * 4 + ks) * 65 + lane) * 8);
                o1 = __builtin_amdgcn_mfma_f32_32x32x16_bf16(pa[ks], vf1, o1, 0, 0, 0);
            }
            __builtin_amdgcn_s_setprio(0);
        }

        kti = kti_next;
        if (step < 7 && (i + 1) == bound) {   // q-tile crossing: flush + reset
            FLUSH(0);
            o0 = (f32x16)0.0f; o1 = (f32x16)0.0f; l_acc = 0.0f;
            qt = qtB; qrow0 = qt * 128 + w * 32;
            #pragma unroll
            for (int ds = 0; ds < 4; ++ds)
                qf[ds] = *(const bf16x8*)(qs + (base + qrow0 + l31) * HD_ + ds * 16 + hi * 8);
        }
    }
    FLUSH((t0 + 7 >= bound) ? 1 : 0);
}

// ---------------------------------------------------------------------------
// Kernel 3: merge partials. grid = (b, qt2, row-half) = 256 blocks.
// Chunk ranges re-derived for chunk=8 (case-verified at qt2=0,15,16,30,31).
// ---------------------------------------------------------------------------
__global__ __launch_bounds__(256) void merge_kernel(
    const float* __restrict__ pl, const u16* __restrict__ pO,
    float* __restrict__ out)
{
    const int bi  = blockIdx.x;            // b*64 + qt2*2 + rh
    const int rh  = bi & 1;
    const int qt2 = (bi >> 1) & 31;
    const int b   = bi >> 6;

    int c0, c1, role, mbase;
    if (qt2 <= 14)      { int u = qt2;      c0 = 0;                c1 = (2 * u + 1) >> 3; role = 0; mbase = u * 8; }
    else if (qt2 == 15) { c0 = 0;           c1 = 3;                role = 0; mbase = 120; }
    else if (qt2 <= 30) { int u = 30 - qt2; c0 = (2 * u + 2) >> 3; c1 = 7;  role = 1; mbase = u * 8; }
    else                { c0 = 0;           c1 = 7;                role = 0; mbase = 124; }

    const int row = rh * 64 + (threadIdx.x >> 2);
    const int hg  = (threadIdx.x & 3) * 16;

    float L = 0.0f;
    float o[16];
    #pragma unroll
    for (int i = 0; i < 16; ++i) o[i] = 0.0f;
    for (int c = c0; c <= c1; ++c) {
        const int slot = (b * CPB_ + mbase + c) * 2 + role;
        L += pl[slot * 128 + row];
        const u16* p = pO + (size_t)slot * 8192 + row * 64 + hg;
        bf16x8 v0 = *(const bf16x8*)p;
        bf16x8 v1 = *(const bf16x8*)(p + 8);
        #pragma unroll
        for (int i = 0; i < 8; ++i) { o[i] += bf2f((u16)v0[i]); o[8 + i] += bf2f((u16)v1[i]); }
    }
    const float inv = 1.0f / L;
    float* op = out + ((size_t)b * T_ + qt2 * 128 + row) * HD_ + hg;
    #pragma unroll
    for (int j = 0; j < 4; ++j) {
        f32x4 v;
        #pragma unroll
        for (int i = 0; i < 4; ++i) v[i] = o[j * 4 + i] * inv;
        *(f32x4*)(op + j * 4) = v;
    }
}

extern "C" void kernel_launch(void* const* d_in, const int* in_sizes, int n_in,
                              void* d_out, int out_size, void* d_ws, size_t ws_size,
                              hipStream_t stream) {
    const float* x  = (const float*)d_in[0];
    const float* wq = (const float*)d_in[1];
    const float* wk = (const float*)d_in[2];
    const float* wv = (const float*)d_in[3];

    const size_t NE = (size_t)BT_ * HD_;           // 1,048,576
    char* ws = (char*)d_ws;
    u16* qs   = (u16*)ws;                          // 2 MB (Q pre-scaled)
    u16* kss  = qs  + NE;                          // 2 MB
    u16* vssT = kss + NE;                          // 2 MB, [h][B*T]
    u16* wb   = vssT + NE;                         // 384 KB bf16 W (row-major)
    float* pl = (float*)(wb + 192 * 1024);         // NSLOT_*128 f32 = 540 KB
    u16* pO   = (u16*)(pl + (size_t)NSLOT_ * 128); // NSLOT_*8192 bf16 = 17.3 MB
    float* out = (float*)d_out;

    wconv_kernel<<<dim3(96),        dim3(256), 0, stream>>>(wq, wk, wv, wb);
    qkv_kernel  <<<dim3(256),       dim3(512), 0, stream>>>(x, wb, qs, kss, vssT);
    attn_kernel <<<dim3(4 * CPB_),  dim3(256), 0, stream>>>(qs, kss, vssT, pl, pO);
    merge_kernel<<<dim3(256),       dim3(256), 0, stream>>>(pl, pO, out);
}

// Round 12
// 145.505 us; speedup vs baseline: 1.1740x; 1.0041x over previous
//
#include <hip/hip_runtime.h>
#include <stdint.h>

#define B_  4
#define T_  4096
#define D_  1024
#define HD_ 64
#define BT_ 16384   // B_*T_

typedef short bf16x8 __attribute__((ext_vector_type(8)));
typedef float f32x4  __attribute__((ext_vector_type(4)));
typedef float f32x16 __attribute__((ext_vector_type(16)));
typedef unsigned short u16;
typedef u16 u16x4 __attribute__((ext_vector_type(4)));
typedef unsigned int u32;
typedef u32 u32x4 __attribute__((ext_vector_type(4)));

#define M0L2_  11.54156032f  // M0(=8) * log2(e)
#define QSCALE_ 0.18033688f  // 0.125 * log2(e): folds softmax scale AND exp2 base

#define CPB_   132           // chunks (=attn blocks) per batch, 8 tile-tasks each
#define NSLOT_ (4 * CPB_ * 2)

__device__ __forceinline__ u16 f2bf(float f) {
    union { float f; unsigned u; } v; v.f = f;
    unsigned r = (v.u + 0x7FFF + ((v.u >> 16) & 1)) >> 16;
    return (u16)r;
}
__device__ __forceinline__ float bf2f(u16 u) {
    union { unsigned u; float f; } v; v.u = ((unsigned)u) << 16;
    return v.f;
}
// packed f32x2 -> bf16x2 (lo = first operand)
__device__ __forceinline__ u32 cvt_pk_bf16(float lo, float hi) {
    u32 r;
    asm("v_cvt_pk_bf16_f32 %0, %1, %2" : "=v"(r) : "v"(lo), "v"(hi));
    return r;
}
// 16B global -> LDS direct (no VGPR round-trip). LDS dest: uniform base + lane*16.
__device__ __forceinline__ void gload_lds16(const void* g, void* l) {
    __builtin_amdgcn_global_load_lds(
        (const __attribute__((address_space(1))) unsigned int*)g,
        (__attribute__((address_space(3))) unsigned int*)l, 16, 0, 0);
}

// ---------------------------------------------------------------------------
// Kernel 0: W fp32 -> bf16, PRE-SWIZZLED granule layout for global_load_lds.
// Granule (16B = 8 bf16): original (n, kg) stored at n*128 + (kg&~7) |
// ((kg&7) ^ (n&7)). qkv reads wb LINEARLY into linear LDS, and recovers via
// the read-side XOR — the swizzle is applied ONCE on each side (round-11 bug
// was applying it twice on the write path: wconv swizzle + qkv source XOR
// cancelled, then the read XOR corrupted).
// ---------------------------------------------------------------------------
__global__ __launch_bounds__(256) void wconv_kernel(
    const float* __restrict__ wq, const float* __restrict__ wk,
    const float* __restrict__ wv, u16* __restrict__ wb)
{
    const int cid = blockIdx.x * 256 + threadIdx.x;   // 96 blocks -> 24576 granules
    const int n   = cid >> 7;          // 0..191
    const int kg  = cid & 127;         // k-granule 0..127
    const int mat = n >> 6, row = n & 63;
    const float* src = (mat == 0) ? wq : ((mat == 1) ? wk : wv);
    const float* p = src + row * 1024 + kg * 8;
    f32x4 a0 = *(const f32x4*)p;
    f32x4 a1 = *(const f32x4*)(p + 4);
    u32x4 b;
    b[0] = cvt_pk_bf16(a0[0], a0[1]);
    b[1] = cvt_pk_bf16(a0[2], a0[3]);
    b[2] = cvt_pk_bf16(a1[0], a1[1]);
    b[3] = cvt_pk_bf16(a1[2], a1[3]);
    const int dkg = (kg & ~7) | ((kg & 7) ^ (n & 7));
    *(u32x4*)(wb + ((size_t)n * 128 + dkg) * 8) = b;
}

// ---------------------------------------------------------------------------
// Kernel 1: QKV projection — 64-row tiles, 512 threads, double-buffered LDS.
// W staged via global_load_lds width=16: no VGPR round-trip, no ds_write
// issue stream. wb read LINEARLY (content pre-swizzled by wconv) into LINEAR
// LDS [1536*16B]; fragment reads XOR-swizzled (valid since n&7 == l16&7) ->
// conflict-free at the wave64 b128 minimum (8 words/bank).
// x keeps reg+cvt_pk path into padded xt (fp32->bf16 conversion required).
// Emits: qs[row][h] (x 0.125*log2e), kss[row][h], vssT[h][row] (transposed).
// ---------------------------------------------------------------------------
__global__ __launch_bounds__(512, 2) void qkv_kernel(
    const float* __restrict__ x, const u16* __restrict__ wb,
    u16* __restrict__ qs, u16* __restrict__ kss, u16* __restrict__ vssT)
{
    __shared__ __align__(16) u16 xt[2][64][72];
    __shared__ __align__(16) u16 wt[2][1536 * 8];   // linear dest, swizzled content

    const int tid  = threadIdx.x;
    const int lane = tid & 63;
    const int w    = tid >> 6;          // 0..7
    const int quad = lane >> 4;
    const int l16  = lane & 15;
    const int row0 = blockIdx.x * 64;
    const int rh   = w >> 2;            // row-half (32 rows)
    const int ct   = w & 3;             // col-triple (3 col-groups of 16)

    const int xrow = tid >> 3;          // 0..63  (x staging row)
    const int xcg  = tid & 7;           // col-group *8

    f32x4 acc[2][3];
    #pragma unroll
    for (int s = 0; s < 2; ++s)
        #pragma unroll
        for (int g = 0; g < 3; ++g) acc[s][g] = (f32x4)0.0f;

    const float* xbase = x + (size_t)(row0 + xrow) * D_ + xcg * 8;

    // W chunk geometry: chunk c = tid + 512*i, n = c>>3, cg = c&7.
    // LINEAR source granule n*128 + t*8 + cg (content already pre-swizzled).
    const u16* wsrc[3];
    u16* wdst[3];
    #pragma unroll
    for (int i = 0; i < 3; ++i) {
        const int c = tid + 512 * i;
        wsrc[i] = wb + (size_t)c * 8 * 16;        // n*128*8 + cg*8 u16 (c = n*8+cg)
        wdst[i] = (u16*)wt + (size_t)c * 8;       // + buf*12288
    }
    // note: c*8*16 u16? c = n*8 + cg -> granule index n*128 + cg needs
    // n*128 + cg = (c>>3)*128 + (c&7). Compute explicitly instead:
    #pragma unroll
    for (int i = 0; i < 3; ++i) {
        const int c = tid + 512 * i;
        const int n = c >> 3, cg = c & 7;
        wsrc[i] = wb + ((size_t)n * 128 + cg) * 8;   // + t*64 u16 per tile
    }

    f32x4 xa, xb;
    auto xload = [&](int t) {
        const float* xp = xbase + t * 64;
        xa = *(const f32x4*)xp; xb = *(const f32x4*)(xp + 4);
    };
    auto xstore = [&](int bufi) {
        u32x4 px;
        px[0] = cvt_pk_bf16(xa[0], xa[1]);
        px[1] = cvt_pk_bf16(xa[2], xa[3]);
        px[2] = cvt_pk_bf16(xb[0], xb[1]);
        px[3] = cvt_pk_bf16(xb[2], xb[3]);
        *(u32x4*)&xt[bufi][xrow][xcg * 8] = px;
    };
    auto wload = [&](int t, int bufi) {
        #pragma unroll
        for (int i = 0; i < 3; ++i)
            gload_lds16(wsrc[i] + t * 64, wdst[i] + bufi * 12288);
    };
    auto compute = [&](int bufi) {
        #pragma unroll
        for (int ks = 0; ks < 2; ++ks) {
            bf16x8 a[2];
            #pragma unroll
            for (int s = 0; s < 2; ++s)
                a[s] = *(const bf16x8*)&xt[bufi][rh * 32 + s * 16 + l16][ks * 32 + quad * 8];
            #pragma unroll
            for (int g = 0; g < 3; ++g) {
                const int n = (ct * 3 + g) * 16 + l16;
                // swizzled read recovers linear fragment (n&7 == l16&7)
                bf16x8 bfr = *(const bf16x8*)&wt[bufi][n * 64 + ((ks * 32 + quad * 8) ^ ((l16 & 7) * 8))];
                #pragma unroll
                for (int s = 0; s < 2; ++s)
                    acc[s][g] = __builtin_amdgcn_mfma_f32_16x16x32_bf16(a[s], bfr, acc[s][g], 0, 0, 0);
            }
        }
    };

    // prologue: tile 0 into buffer 0
    xload(0);
    wload(0, 0);
    xstore(0);
    __syncthreads();   // drains vmcnt (gload_lds) + lgkm (ds_write)

    for (int kc = 0; kc < 16; ++kc) {
        const int cur = kc & 1;
        if (kc < 15) {
            wload(kc + 1, cur ^ 1);   // direct-to-LDS, no register consumer
            xload(kc + 1);
        }
        compute(cur);
        if (kc < 15) xstore(cur ^ 1);
        __syncthreads();
    }

    // epilogue: C/D layout row=quad*4+r, col=l16
    #pragma unroll
    for (int s = 0; s < 2; ++s) {
        #pragma unroll
        for (int g = 0; g < 3; ++g) {
            const int n = (ct * 3 + g) * 16 + l16;
            const int j = n >> 6, h = n & 63;
            const int rbase = row0 + rh * 32 + s * 16 + quad * 4;
            if (j == 0) {
                #pragma unroll
                for (int r = 0; r < 4; ++r) qs[(size_t)(rbase + r) * HD_ + h] = f2bf(acc[s][g][r] * QSCALE_);
            } else if (j == 1) {
                #pragma unroll
                for (int r = 0; r < 4; ++r) kss[(size_t)(rbase + r) * HD_ + h] = f2bf(acc[s][g][r]);
            } else {
                u16x4 v;
                #pragma unroll
                for (int r = 0; r < 4; ++r) v[r] = f2bf(acc[s][g][r]);
                *(u16x4*)(vssT + (size_t)h * BT_ + rbase) = v;   // transposed store
            }
        }
    }
}

// ---------------------------------------------------------------------------
// Kernel 2: flash attention, 32x32 swapped-QK, P fully in registers.
// (unchanged from round 10 — verified; chunk=8, 528 blocks)
// ---------------------------------------------------------------------------
__global__ __launch_bounds__(256, 4) void attn_kernel(
    const u16* __restrict__ qs, const u16* __restrict__ kss,
    const u16* __restrict__ vssT,
    float* __restrict__ pl, u16* __restrict__ pO)
{
    __shared__ __align__(16) u16 kt2[8 * 65 * 8];
    __shared__ __align__(16) u16 vt2[8 * 65 * 8];

    const int m = blockIdx.x % CPB_;
    const int b = blockIdx.x / CPB_;

    int t0, bound, qtA, qtB;
    if (m < 120)      { int u = m >> 3; t0 = (m & 7) * 8; bound = 2 * u + 2; qtA = u;  qtB = 30 - u; }
    else if (m < 124) { t0 = (m - 120) * 8; bound = 1 << 30; qtA = 15; qtB = 15; }
    else              { t0 = (m - 124) * 8; bound = 1 << 30; qtA = 31; qtB = 31; }

    const int tid  = threadIdx.x;
    const int lane = tid & 63;
    const int w    = tid >> 6;
    const int l31  = lane & 31;
    const int hi   = lane >> 5;
    const size_t base = (size_t)b * T_;

    int qt    = (t0 < bound) ? qtA : qtB;
    int kti   = (t0 < bound) ? t0 : (t0 - bound);
    int qrow0 = qt * 128 + w * 32;

    // Q B-frags: lane holds Q[q=l31][ds*16 + hi*8 + 0..7]
    bf16x8 qf[4];
    #pragma unroll
    for (int ds = 0; ds < 4; ++ds)
        qf[ds] = *(const bf16x8*)(qs + (base + qrow0 + l31) * HD_ + ds * 16 + hi * 8);

    f32x16 o0 = (f32x16)0.0f, o1 = (f32x16)0.0f;
    float l_acc = 0.0f;

    // staging: thread t -> row t>>2 (key for K / d for V), 32B at col (t&3)*16
    const int srow = tid >> 2, q4 = tid & 3;
    const u16* kp = kss  + (base + srow) * HD_ + q4 * 16;
    const u16* vp = vssT + (size_t)srow * BT_ + base + q4 * 16;
    u16* kdst = kt2 + ((((srow >> 5) * 4 + q4) * 65 + (srow & 31)) * 8);
    u16* vdst = vt2 + ((((srow >> 5) * 4 + q4) * 65 + (srow & 31)) * 8);

    bf16x8 kr0, kr1, vr0, vr1;
    {
        const u16* k0 = kp + (size_t)kti * 64 * HD_;
        kr0 = *(const bf16x8*)k0; kr1 = *(const bf16x8*)(k0 + 8);
        const u16* v0 = vp + kti * 64;
        vr0 = *(const bf16x8*)v0; vr1 = *(const bf16x8*)(v0 + 8);
    }

    auto FLUSH = [&](int role) {
        const int slot = (b * CPB_ + m) * 2 + role;
        u32 la = __builtin_bit_cast(u32, l_acc), lb = la;
        asm("v_permlane32_swap_b32 %0, %1" : "+v"(la), "+v"(lb));
        float lfull = __builtin_bit_cast(float, la) + __builtin_bit_cast(float, lb);
        if (hi == 0) pl[slot * 128 + w * 32 + l31] = lfull;
        #pragma unroll
        for (int reg = 0; reg < 16; ++reg) {
            int row = w * 32 + (reg & 3) + 8 * (reg >> 2) + 4 * hi;
            pO[(size_t)slot * 8192 + row * 64 + l31]      = f2bf(o0[reg]);
            pO[(size_t)slot * 8192 + row * 64 + 32 + l31] = f2bf(o1[reg]);
        }
    };

    for (int step = 0; step < 8; ++step) {
        const int i = t0 + step;
        __syncthreads();
        *(bf16x8*)(kdst)       = kr0;
        *(bf16x8*)(kdst + 256) = kr1;
        *(bf16x8*)(vdst)       = vr0;
        *(bf16x8*)(vdst + 256) = vr1;
        __syncthreads();

        int kti_next = 0;
        if (step < 7) {
            kti_next = (i + 1 < bound) ? (i + 1) : (i + 1 - bound);
            const u16* k0 = kp + (size_t)kti_next * 64 * HD_;
            kr0 = *(const bf16x8*)k0; kr1 = *(const bf16x8*)(k0 + 8);
            const u16* v0 = vp + kti_next * 64;
            vr0 = *(const bf16x8*)v0; vr1 = *(const bf16x8*)(v0 + 8);
        }

        if (kti * 64 <= qrow0 + 31) {      // warp-uniform skip of fully-masked tiles
            const bool diag = (kti * 64 + 63 > qrow0);
            const int  qa   = qrow0 + l31;
            u32 wv[16];
            #pragma unroll
            for (int kg = 0; kg < 2; ++kg) {
                f32x16 s = (f32x16)0.0f;
                __builtin_amdgcn_s_setprio(1);
                #pragma unroll
                for (int ds = 0; ds < 4; ++ds) {
                    bf16x8 af = *(const bf16x8*)(kt2 + ((kg * 4 + ds) * 65 + lane) * 8);
                    s = __builtin_amdgcn_mfma_f32_32x32x16_bf16(af, qf[ds], s, 0, 0, 0);
                }
                __builtin_amdgcn_s_setprio(0);
                float lp = 0.0f;
                #pragma unroll
                for (int rp = 0; rp < 8; ++rp) {
                    float e0 = __builtin_amdgcn_exp2f(s[2 * rp]     - M0L2_);
                    float e1 = __builtin_amdgcn_exp2f(s[2 * rp + 1] - M0L2_);
                    if (diag) {
                        const int k0e = kti * 64 + kg * 32 + ((2 * rp) & 3) + 8 * ((2 * rp) >> 2) + 4 * hi;
                        if (k0e > qa)     e0 = 0.0f;
                        if (k0e + 1 > qa) e1 = 0.0f;   // reg 2rp+1 = key k0e+1
                    }
                    lp += e0 + e1;
                    wv[kg * 8 + rp] = cvt_pk_bf16(e0, e1);
                }
                l_acc += lp;
            }
            // PA frags: one swap fills two output words (guide §B recipe)
            bf16x8 pa[4];
            #pragma unroll
            for (int ks = 0; ks < 4; ++ks) {
                const int kg2 = ks >> 1, k1 = ks & 1;
                u32 x0 = wv[kg2 * 8 + k1 * 4 + 0], y0 = wv[kg2 * 8 + k1 * 4 + 2];
                u32 x1 = wv[kg2 * 8 + k1 * 4 + 1], y1 = wv[kg2 * 8 + k1 * 4 + 3];
                asm("v_permlane32_swap_b32 %0, %1" : "+v"(x0), "+v"(y0));
                asm("v_permlane32_swap_b32 %0, %1" : "+v"(x1), "+v"(y1));
                u32x4 t; t[0] = x0; t[1] = x1; t[2] = y0; t[3] = y1;
                pa[ks] = __builtin_bit_cast(bf16x8, t);
            }
            __builtin_amdgcn_s_setprio(1);
            #pragma unroll
            for (int ks = 0; ks < 4; ++ks) {
                bf16x8 vf0 = *(const bf16x8*)(vt2 + ((0 * 4 + ks) * 65 + lane) * 8);
                o0 = __builtin_amdgcn_mfma_f32_32x32x16_bf16(pa[ks], vf0, o0, 0, 0, 0);
                bf16x8 vf1 = *(const bf16x8*)(vt2 + ((1 * 4 + ks) * 65 + lane) * 8);
                o1 = __builtin_amdgcn_mfma_f32_32x32x16_bf16(pa[ks], vf1, o1, 0, 0, 0);
            }
            __builtin_amdgcn_s_setprio(0);
        }

        kti = kti_next;
        if (step < 7 && (i + 1) == bound) {   // q-tile crossing: flush + reset
            FLUSH(0);
            o0 = (f32x16)0.0f; o1 = (f32x16)0.0f; l_acc = 0.0f;
            qt = qtB; qrow0 = qt * 128 + w * 32;
            #pragma unroll
            for (int ds = 0; ds < 4; ++ds)
                qf[ds] = *(const bf16x8*)(qs + (base + qrow0 + l31) * HD_ + ds * 16 + hi * 8);
        }
    }
    FLUSH((t0 + 7 >= bound) ? 1 : 0);
}

// ---------------------------------------------------------------------------
// Kernel 3: merge partials. grid = (b, qt2, row-half) = 256 blocks.
// (unchanged from round 10 — verified)
// ---------------------------------------------------------------------------
__global__ __launch_bounds__(256) void merge_kernel(
    const float* __restrict__ pl, const u16* __restrict__ pO,
    float* __restrict__ out)
{
    const int bi  = blockIdx.x;            // b*64 + qt2*2 + rh
    const int rh  = bi & 1;
    const int qt2 = (bi >> 1) & 31;
    const int b   = bi >> 6;

    int c0, c1, role, mbase;
    if (qt2 <= 14)      { int u = qt2;      c0 = 0;                c1 = (2 * u + 1) >> 3; role = 0; mbase = u * 8; }
    else if (qt2 == 15) { c0 = 0;           c1 = 3;                role = 0; mbase = 120; }
    else if (qt2 <= 30) { int u = 30 - qt2; c0 = (2 * u + 2) >> 3; c1 = 7;  role = 1; mbase = u * 8; }
    else                { c0 = 0;           c1 = 7;                role = 0; mbase = 124; }

    const int row = rh * 64 + (threadIdx.x >> 2);
    const int hg  = (threadIdx.x & 3) * 16;

    float L = 0.0f;
    float o[16];
    #pragma unroll
    for (int i = 0; i < 16; ++i) o[i] = 0.0f;
    for (int c = c0; c <= c1; ++c) {
        const int slot = (b * CPB_ + mbase + c) * 2 + role;
        L += pl[slot * 128 + row];
        const u16* p = pO + (size_t)slot * 8192 + row * 64 + hg;
        bf16x8 v0 = *(const bf16x8*)p;
        bf16x8 v1 = *(const bf16x8*)(p + 8);
        #pragma unroll
        for (int i = 0; i < 8; ++i) { o[i] += bf2f((u16)v0[i]); o[8 + i] += bf2f((u16)v1[i]); }
    }
    const float inv = 1.0f / L;
    float* op = out + ((size_t)b * T_ + qt2 * 128 + row) * HD_ + hg;
    #pragma unroll
    for (int j = 0; j < 4; ++j) {
        f32x4 v;
        #pragma unroll
        for (int i = 0; i < 4; ++i) v[i] = o[j * 4 + i] * inv;
        *(f32x4*)(op + j * 4) = v;
    }
}

extern "C" void kernel_launch(void* const* d_in, const int* in_sizes, int n_in,
                              void* d_out, int out_size, void* d_ws, size_t ws_size,
                              hipStream_t stream) {
    const float* x  = (const float*)d_in[0];
    const float* wq = (const float*)d_in[1];
    const float* wk = (const float*)d_in[2];
    const float* wv = (const float*)d_in[3];

    const size_t NE = (size_t)BT_ * HD_;           // 1,048,576
    char* ws = (char*)d_ws;
    u16* qs   = (u16*)ws;                          // 2 MB (Q pre-scaled)
    u16* kss  = qs  + NE;                          // 2 MB
    u16* vssT = kss + NE;                          // 2 MB, [h][B*T]
    u16* wb   = vssT + NE;                         // 384 KB bf16 W (swizzled granules)
    float* pl = (float*)(wb + 192 * 1024);         // NSLOT_*128 f32 = 540 KB
    u16* pO   = (u16*)(pl + (size_t)NSLOT_ * 128); // NSLOT_*8192 bf16 = 17.3 MB
    float* out = (float*)d_out;

    wconv_kernel<<<dim3(96),        dim3(256), 0, stream>>>(wq, wk, wv, wb);
    qkv_kernel  <<<dim3(256),       dim3(512), 0, stream>>>(x, wb, qs, kss, vssT);
    attn_kernel <<<dim3(4 * CPB_),  dim3(256), 0, stream>>>(qs, kss, vssT, pl, pO);
    merge_kernel<<<dim3(256),       dim3(256), 0, stream>>>(pl, pO, out);
}